// Round 21
// baseline (446.898 us; speedup 1.0000x reference)
//
#include <hip/hip_runtime.h>
#include <hip/hip_bf16.h>
#include <math.h>

#define B_ 4
#define L_ 1024
#define DM 512
#define NH 8
#define HD 64
#define DFF 2048
#define KS 35
#define QS 1536   // packed QKV row stride
#define CH 128    // attention key chunk
#define NCH (L_/CH)
#define VSEG 16   // V-mean segments per head

typedef __attribute__((ext_vector_type(8))) short bf16x8;
typedef __attribute__((ext_vector_type(4))) float f32x4;

__device__ inline ushort f2b(float f){
  __hip_bfloat16 h = __float2bfloat16(f);
  return *reinterpret_cast<ushort*>(&h);
}
__device__ inline float b2f(ushort u){
  union { unsigned int i; float f; } x; x.i = ((unsigned int)u) << 16; return x.f;
}
__device__ inline float gelu_exact(float x){
  return 0.5f*x*(1.0f+erff(x*0.7071067811865476f));
}

#define GLOAD16(g, l) __builtin_amdgcn_global_load_lds( \
    (const __attribute__((address_space(1))) void*)(g), \
    (__attribute__((address_space(3))) void*)(l), 16, 0, 0)

// ---------------- weight convert + transpose to bf16 [N][K] (layer-batched) ----------
__global__ __launch_bounds__(256) void wconv_kernel(const float* __restrict__ W,
    ushort* __restrict__ Wt, int K, int N, size_t sStride, size_t dStride)
{
  W  += (size_t)blockIdx.z * sStride;
  Wt += (size_t)blockIdx.z * dStride;
  __shared__ float tile[32][33];
  int n0 = blockIdx.x*32, k0 = blockIdx.y*32;
  int tx = threadIdx.x & 31, ty = threadIdx.x >> 5;
  #pragma unroll
  for (int i = ty; i < 32; i += 8) tile[i][tx] = W[(size_t)(k0+i)*N + n0+tx];
  __syncthreads();
  #pragma unroll
  for (int i = ty; i < 32; i += 8) Wt[(size_t)(n0+i)*K + k0+tx] = f2b(tile[tx][i]);
}

// QKV variant: z in [0,6) = which*2 + layer; one dispatch for all six 512x512 blocks
__global__ __launch_bounds__(256) void wconv_qkv_kernel(const float* __restrict__ Wq,
    const float* __restrict__ Wk, const float* __restrict__ Wv, ushort* __restrict__ Wt)
{
  int z = blockIdx.z, which = z >> 1, l = z & 1;
  const float* W = ((which == 0) ? Wq : (which == 1) ? Wk : Wv) + (size_t)l*DM*DM;
  ushort* dst = Wt + (size_t)l*QS*DM + (size_t)which*512*DM;
  __shared__ float tile[32][33];
  int n0 = blockIdx.x*32, k0 = blockIdx.y*32;
  int tx = threadIdx.x & 31, ty = threadIdx.x >> 5;
  #pragma unroll
  for (int i = ty; i < 32; i += 8) tile[i][tx] = W[(size_t)(k0+i)*DM + n0+tx];
  __syncthreads();
  #pragma unroll
  for (int i = ty; i < 32; i += 8) dst[(size_t)(n0+i)*DM + k0+tx] = f2b(tile[tx][i]);
}

__global__ __launch_bounds__(256) void bcat_kernel(const float* __restrict__ bq,
    const float* __restrict__ bk, const float* __restrict__ bv, float* __restrict__ bqkv)
{
  int i = blockIdx.x*256 + threadIdx.x;   // 0..3071
  if (i >= 2*QS) return;
  int l = i / QS, j = i - l*QS;
  const float* src = (j < 512) ? bq : (j < 1024 ? bk : bv);
  bqkv[i] = src[l*DM + (j & 511)];
}

// ---------------- bf16 MFMA GEMM: dbuf, K=64/tile, COUNTED vmcnt (T4), XCD-swizzled --
// MODE 0: f32 out, 1: gelu->bf16 out, 2: +R f32 out, 3: plain bf16 out
template<int BM, int BN, int MODE>
__global__ __launch_bounds__(256) void mfma_gemm(
    const ushort* __restrict__ A, const ushort* __restrict__ Bt,
    const float* __restrict__ bias, const float* __restrict__ R,
    float* __restrict__ Cf, ushort* __restrict__ Cb,
    int M, int N, int K)
{
  constexpr int MF = BM/32;          // A fragments per wave
  constexpr int NF = BN/32;          // B fragments per wave
  constexpr int AIT = BM*4/256;      // staging iters per K=32 sub-tile
  constexpr int BIT = BN*4/256;
  constexpr int LT = (AIT + BIT)*2;  // gload_lds ops per K=64 tile per thread (4/6/8)
  __shared__ __align__(16) ushort As[2][2][BM*32];
  __shared__ __align__(16) ushort Bs[2][2][BN*32];
  const int t = threadIdx.x, lane = t & 63, w = t >> 6, wr = w >> 1, wc = w & 1;

  // XCD-chunked bijective swizzle (all grids are multiples of 8)
  const int gx = gridDim.x;
  const int nwg = gx * gridDim.y;
  const int bid = blockIdx.y*gx + blockIdx.x;
  const int swz = (bid & 7)*(nwg >> 3) + (bid >> 3);
  const int row0 = (swz / gx)*BM, col0 = (swz % gx)*BN;

  // staging: linear LDS dest, inverse-swizzled global source (per K=32 sub-tile)
  const ushort* aSrc[AIT]; int aDst[AIT];
  #pragma unroll
  for (int j = 0; j < AIT; j++) {
    int ch = j*256 + t, r = ch >> 2, cc = ch & 3, cs = cc ^ ((r >> 1) & 3);
    aSrc[j] = A + (size_t)(row0 + r)*K + cs*8;
    aDst[j] = ch*16;
  }
  const ushort* bSrc[BIT]; int bDst[BIT];
  #pragma unroll
  for (int j = 0; j < BIT; j++) {
    int ch = j*256 + t, r = ch >> 2, cc = ch & 3, cs = cc ^ ((r >> 1) & 3);
    bSrc[j] = Bt + (size_t)(col0 + r)*K + cs*8;
    bDst[j] = ch*16;
  }
  // fragment read offsets (swizzled, within one sub-tile)
  int aOff[MF], bOff[NF];
  #pragma unroll
  for (int m = 0; m < MF; m++) {
    int r = wr*(BM/2) + m*16 + (lane & 15);
    aOff[m] = r*64 + (((lane >> 4)*16) ^ (((r >> 1) & 3) << 4));
  }
  #pragma unroll
  for (int n = 0; n < NF; n++) {
    int r = wc*(BN/2) + n*16 + (lane & 15);
    bOff[n] = r*64 + (((lane >> 4)*16) ^ (((r >> 1) & 3) << 4));
  }
  f32x4 zero = {0.f, 0.f, 0.f, 0.f};
  f32x4 acc[MF][NF];
  #pragma unroll
  for (int m = 0; m < MF; m++)
    #pragma unroll
    for (int n = 0; n < NF; n++) acc[m][n] = zero;

#define STAGE_TILE(kt, buf) do { \
    _Pragma("unroll") \
    for (int j = 0; j < AIT; j++) GLOAD16(aSrc[j] + (kt),      (char*)As[buf][0] + aDst[j]); \
    _Pragma("unroll") \
    for (int j = 0; j < AIT; j++) GLOAD16(aSrc[j] + (kt) + 32, (char*)As[buf][1] + aDst[j]); \
    _Pragma("unroll") \
    for (int j = 0; j < BIT; j++) GLOAD16(bSrc[j] + (kt),      (char*)Bs[buf][0] + bDst[j]); \
    _Pragma("unroll") \
    for (int j = 0; j < BIT; j++) GLOAD16(bSrc[j] + (kt) + 32, (char*)Bs[buf][1] + bDst[j]); \
  } while (0)

  const int nk = K >> 6;             // K/64, always >= 8 here
  // prologue: 2-deep prefetch — T0 -> buf0, T1 -> buf1
  STAGE_TILE(0, 0);
  STAGE_TILE(64, 1);

  for (int ki = 0; ki < nk; ki++) {
    const int cur = ki & 1;
    // wait for tile ki's loads; tile ki+1's LT loads may remain in flight (never 0 mid-loop)
    if (ki + 1 < nk) {
      if constexpr (LT == 8)      asm volatile("s_waitcnt vmcnt(8)" ::: "memory");
      else if constexpr (LT == 6) asm volatile("s_waitcnt vmcnt(6)" ::: "memory");
      else                        asm volatile("s_waitcnt vmcnt(4)" ::: "memory");
    } else {
      asm volatile("s_waitcnt vmcnt(0)" ::: "memory");
    }
    __builtin_amdgcn_sched_barrier(0);
    __builtin_amdgcn_s_barrier();      // all waves have tile ki resident
    #pragma unroll
    for (int s = 0; s < 2; s++) {      // two K=32 sub-steps, same accumulation order
      bf16x8 af[MF], bfr[NF];
      #pragma unroll
      for (int m = 0; m < MF; m++) af[m] = *(const bf16x8*)((const char*)As[cur][s] + aOff[m]);
      #pragma unroll
      for (int n = 0; n < NF; n++) bfr[n] = *(const bf16x8*)((const char*)Bs[cur][s] + bOff[n]);
      #pragma unroll
      for (int m = 0; m < MF; m++)
        #pragma unroll
        for (int n = 0; n < NF; n++)
          acc[m][n] = __builtin_amdgcn_mfma_f32_16x16x32_bf16(af[m], bfr[n], acc[m][n], 0, 0, 0);
    }
    __builtin_amdgcn_s_barrier();      // all waves done reading buf[cur]
    if (ki + 2 < nk) STAGE_TILE((ki + 2) << 6, cur);   // refill the just-read buffer
  }
#undef STAGE_TILE

  #pragma unroll
  for (int m = 0; m < MF; m++) {
    int rb = row0 + wr*(BM/2) + m*16 + ((lane >> 4) << 2);
    #pragma unroll
    for (int n = 0; n < NF; n++) {
      int c = col0 + wc*(BN/2) + n*16 + (lane & 15);
      float bv = bias[c];
      #pragma unroll
      for (int j = 0; j < 4; j++) {
        size_t idx = (size_t)(rb + j)*N + c;
        float v = acc[m][n][j] + bv;
        if (MODE == 1)      Cb[idx] = f2b(gelu_exact(v));
        else if (MODE == 2) Cf[idx] = v + R[idx];
        else if (MODE == 3) Cb[idx] = f2b(v);
        else                Cf[idx] = v;
      }
    }
  }
}

// ---------------- embed + positional encoding (bf16 trunk out) ----------------
__global__ __launch_bounds__(512) void embed_kernel(const float* __restrict__ src,
    const float* __restrict__ Wemb, const float* __restrict__ bemb,
    ushort* __restrict__ Xt)
{
  int row = blockIdx.x, l = row & (L_-1), t = threadIdx.x;
  __shared__ float s_src[32];
  if (t < 32) s_src[t] = src[row*32 + t];
  __syncthreads();
  float acc = bemb[t];
  #pragma unroll
  for (int k = 0; k < 32; k++) acc += s_src[k]*Wemb[k*DM + t];
  int i2 = t & ~1;
  float freq = expf((float)i2 * (-9.210340371976184f/512.0f));
  float ang = (float)l * freq;
  acc += (t & 1) ? cosf(ang) : sinf(ang);
  Xt[(size_t)row*DM + t] = f2b(acc);
}

// ---------------- QK_sample -> M score (bf16 QKV, j-parallel) ----------------
__global__ __launch_bounds__(64) void qksample_kernel(const ushort* __restrict__ QKVb,
    const int* __restrict__ idx_s, float* __restrict__ Msc)
{
  int gid = blockIdx.x;              // (b*8+h)*1024 + i
  int i = gid & (L_-1), h = (gid >> 10) & 7, b = gid >> 13;
  int t = threadIdx.x;
  int j4 = t >> 2, e4 = t & 3;       // lane = j4*4 + e4
  const ushort* Qrow = QKVb + ((size_t)(b*L_ + i))*QS + h*HD + e4*16;
  bf16x8 qa = *(const bf16x8*)(Qrow);
  bf16x8 qb = *(const bf16x8*)(Qrow + 8);
  float q[16];
  #pragma unroll
  for (int x = 0; x < 8; x++) { q[x] = b2f((ushort)qa[x]); q[8+x] = b2f((ushort)qb[x]); }
  const ushort* Kbase = QKVb + 512 + h*HD + (size_t)b*L_*QS + e4*16;
  const int* idq = idx_s + i*KS;
  float mx = -3.4e38f, sm = 0.f;
  #pragma unroll
  for (int p = 0; p < 3; p++) {
    int j = p*16 + j4;
    int jc = (j < KS) ? j : 0;       // inactive lanes redo j=0 (result discarded)
    int s = idq[jc];
    const ushort* Kr = Kbase + (size_t)s*QS;
    bf16x8 ka = *(const bf16x8*)(Kr);
    bf16x8 kb = *(const bf16x8*)(Kr + 8);
    float d = 0.f;
    #pragma unroll
    for (int x = 0; x < 8; x++) d += q[x]   * b2f((ushort)ka[x]);
    #pragma unroll
    for (int x = 0; x < 8; x++) d += q[8+x] * b2f((ushort)kb[x]);
    d += __shfl_xor(d, 1);
    d += __shfl_xor(d, 2);
    if (j < KS && e4 == 0) { mx = fmaxf(mx, d); sm += d; }
  }
  #pragma unroll
  for (int off = 4; off < 64; off <<= 1) {
    mx = fmaxf(mx, __shfl_xor(mx, off));
    sm += __shfl_xor(sm, off);
  }
  if (t == 0) Msc[gid] = mx - sm*(1.0f/KS);
}

// ---------------- register-resident top-35 (tie-break lower index) ----------------
__global__ __launch_bounds__(64) void topk_kernel(const float* __restrict__ Msc, int* __restrict__ idx_top)
{
  int bh = blockIdx.x, t = threadIdx.x;
  float v[16];
  #pragma unroll
  for (int r = 0; r < 16; r++) v[r] = Msc[(size_t)bh*L_ + r*64 + t];
  for (int sel = 0; sel < KS; sel++) {
    float bv = -3.4e38f; int br = 0;
    #pragma unroll
    for (int r = 0; r < 16; r++) {
      bool gt = v[r] > bv;
      bv = gt ? v[r] : bv;
      br = gt ? r : br;
    }
    int bi = br*64 + t;
    #pragma unroll
    for (int off = 32; off; off >>= 1) {
      float ov = __shfl_xor(bv, off); int oi = __shfl_xor(bi, off);
      if (ov > bv || (ov == bv && oi < bi)) { bv = ov; bi = oi; }
    }
    if (t == 0) idx_top[bh*KS + sel] = bi;
    if ((bi & 63) == t) v[bi >> 6] = -3.4e38f;
  }
}

// ---------------- V mean partials (also zeroes the per-row head mask) ----------------
__global__ __launch_bounds__(64) void vmean_part_kernel(const ushort* __restrict__ QKVb,
    float* __restrict__ VmeanP, int* __restrict__ mask)
{
  int gid = blockIdx.x;              // bh*VSEG + seg  (512 blocks)
  int e = threadIdx.x;
  if (gid < 64) mask[gid*64 + e] = 0;   // zero mask[4096] before build_map (stream-ordered)
  int seg = gid & (VSEG-1), bh = gid >> 4;
  int h = bh & 7, b = bh >> 3;
  const ushort* Vb = QKVb + 1024 + h*HD + ((size_t)(b*L_ + seg*(L_/VSEG)))*QS;
  float s = 0.f;
  for (int l0 = 0; l0 < L_/VSEG; l0 += 8) {
    float vv[8];
    #pragma unroll
    for (int j = 0; j < 8; j++) vv[j] = b2f(Vb[(size_t)(l0+j)*QS + e]);
    #pragma unroll
    for (int j = 0; j < 8; j++) s += vv[j];
  }
  VmeanP[gid*HD + e] = s;
}

__global__ __launch_bounds__(64) void vmean_merge_kernel(const float* __restrict__ VmeanP,
    float* __restrict__ Vmean)
{
  int bh = blockIdx.x, e = threadIdx.x;
  float s = 0.f;
  #pragma unroll
  for (int seg = 0; seg < VSEG; seg++) s += VmeanP[(bh*VSEG + seg)*HD + e];
  Vmean[bh*HD + e] = s * (1.f/L_);
}

// ---------------- build per-row head-selection map (deterministic slots) -------------
__global__ __launch_bounds__(256) void build_map_kernel(const int* __restrict__ idx_top,
    int* __restrict__ mask, int* __restrict__ ent)
{
  int idx = blockIdx.x*256 + threadIdx.x;   // bh*KS + u
  if (idx >= B_*NH*KS) return;
  int bh = idx / KS;
  int b = bh >> 3, h = bh & 7;
  int qi = idx_top[idx];
  int row = b*L_ + qi;
  atomicOr(&mask[row], 1 << h);
  ent[row*8 + h] = idx;                     // unique (row,h) writer -> no race
}

// ---------------- base_b = Vmean_b(concat) @ Wo + bo (f32, per batch) ---------------
__global__ __launch_bounds__(512) void gemv_base_kernel(const float* __restrict__ Vmean,
    const float* __restrict__ Wo_l, const float* __restrict__ bo_l, float* __restrict__ base)
{
  int b = blockIdx.x, c = threadIdx.x;
  __shared__ float vm[512];
  vm[c] = Vmean[b*DM + c];                  // [b*8+h][e] flattens to b*512 + h*64+e
  __syncthreads();
  float acc = bo_l[c];
  for (int e0 = 0; e0 < DM; e0 += 8) {
    float wv[8];
    #pragma unroll
    for (int j = 0; j < 8; j++) wv[j] = Wo_l[(size_t)(e0+j)*DM + c];
    #pragma unroll
    for (int j = 0; j < 8; j++) acc += vm[e0+j]*wv[j];
  }
  base[b*DM + c] = acc;
}

// ---------------- phase B: merge partials -> delta table D (f32) --------------------
__global__ __launch_bounds__(256) void attn_merge_delta_kernel(const float* __restrict__ Pacc,
    const float* __restrict__ Pm, const float* __restrict__ Pl,
    const float* __restrict__ Vmean, float* __restrict__ D)
{
  int bh = blockIdx.x;
  int t = threadIdx.x;
  __shared__ float m8[NCH*35], l8[NCH*35];
  for (int i = t; i < NCH*35; i += 256) {
    int c = i / 35, u = i - c*35;
    m8[c*35 + u] = Pm[((size_t)bh*NCH + c)*35 + u];
    l8[c*35 + u] = Pl[((size_t)bh*NCH + c)*35 + u];
  }
  __syncthreads();
  int e = t & 63, ug = t >> 6;
  float vm = Vmean[bh*HD + e];
  #pragma unroll
  for (int iu = 0; iu < 9; iu++) {
    int u = ug + iu*4;
    if (u >= 35) break;
    float M = -3.4e38f;
    #pragma unroll
    for (int c = 0; c < NCH; c++) M = fmaxf(M, m8[c*35 + u]);
    float Ltot = 0.f, o = 0.f;
    #pragma unroll
    for (int c = 0; c < NCH; c++) {
      float w = expf(m8[c*35 + u] - M);
      Ltot += w * l8[c*35 + u];
      o += w * Pacc[(((size_t)bh*NCH + c)*35 + u)*64 + e];
    }
    D[((size_t)bh*KS + u)*64 + e] = o / Ltot - vm;
  }
}

// ---------------- Ob[row] = base_b + sum_{h in mask} D[(bh,u)] @ Wo_h  (bf16 out) ----
__global__ __launch_bounds__(512) void ob_fill_kernel(const float* __restrict__ base,
    const float* __restrict__ D, const int* __restrict__ mask, const int* __restrict__ ent,
    const float* __restrict__ Wo_l, ushort* __restrict__ Ob)
{
  int l = blockIdx.x, b = l >> 10, c = threadIdx.x;
  float acc = base[b*DM + c];
  int mk = mask[l];
  while (mk) {                              // ascending h -> deterministic order
    int h = __ffs(mk) - 1; mk &= mk - 1;
    int enc = ent[l*8 + h];
    const float* dp = D + (size_t)enc*64;
    const float* wr = Wo_l + (size_t)(h*64)*DM + c;
    #pragma unroll 8
    for (int e = 0; e < 64; e++) acc += dp[e] * wr[(size_t)e*DM];
  }
  Ob[(size_t)l*DM + c] = f2b(acc);
}

// ---------------- chunked flash attention, phase A (bf16 QKV, query-split ×4) ----
// grid: ((b*8+h)*8 + chunk)*4 + q  (1024 blocks), block 256
__global__ __launch_bounds__(256) void attn_part_kernel(const ushort* __restrict__ QKVb,
    const int* __restrict__ idx_top,
    float* __restrict__ Pacc, float* __restrict__ Pm, float* __restrict__ Pl)
{
  int gid = blockIdx.x;
  int q = gid & 3, c = (gid >> 2) & 7, bh = gid >> 5;
  int h = bh & 7, b = bh >> 3;
  int chunk = bh*NCH + c;            // Pacc/Pm/Pl slot (same layout as before)
  int u0 = q*9;
  int NU = (q == 3) ? 8 : 9;
  int t = threadIdx.x;
  __shared__ float qs[9][68];          // scaled Q rows (padded pitch)
  __shared__ float sc[9][132];         // scores -> exp'd scores
  __shared__ float sm[9], sl[9];

  // load + scale this block's Q rows
  for (int idx = t; idx < NU*64; idx += 256) {
    int ul = idx >> 6, e = idx & 63;
    int qi = idx_top[bh*KS + u0 + ul];
    qs[ul][e] = b2f(QKVb[((size_t)(b*L_ + qi))*QS + h*HD + e]) * 0.125f;
  }
  __syncthreads();

  // scores: thread k = t&127 owns one key; K row in 8 bf16x8 regs (convert inline)
  {
    int k = t & 127, par = t >> 7;
    const ushort* Kr = QKVb + ((size_t)(b*L_ + c*CH + k))*QS + 512 + h*HD;
    bf16x8 kreg[8];
    #pragma unroll
    for (int i8 = 0; i8 < 8; i8++) kreg[i8] = *(const bf16x8*)(Kr + i8*8);
    for (int ul = par; ul < NU; ul += 2) {
      float d = 0.f;
      #pragma unroll
      for (int i8 = 0; i8 < 8; i8++) {
        bf16x8 kv = kreg[i8];
        float4 qa = *(const float4*)&qs[ul][i8*8];
        float4 qb = *(const float4*)&qs[ul][i8*8 + 4];
        d += qa.x*b2f((ushort)kv[0]) + qa.y*b2f((ushort)kv[1])
           + qa.z*b2f((ushort)kv[2]) + qa.w*b2f((ushort)kv[3]);
        d += qb.x*b2f((ushort)kv[4]) + qb.y*b2f((ushort)kv[5])
           + qb.z*b2f((ushort)kv[6]) + qb.w*b2f((ushort)kv[7]);
      }
      sc[ul][k] = d;
    }
  }
  __syncthreads();

  // softmax per ul: 4 threads/row
  {
    int ul = t >> 2, sub = t & 3;
    if (ul < NU) {
      float m = -3.4e38f;
      for (int i = sub; i < 128; i += 4) m = fmaxf(m, sc[ul][i]);
      m = fmaxf(m, __shfl_xor(m, 1));
      m = fmaxf(m, __shfl_xor(m, 2));
      float l = 0.f;
      for (int i = sub; i < 128; i += 4) {
        float ev = expf(sc[ul][i] - m);
        sc[ul][i] = ev;
        l += ev;
      }
      l += __shfl_xor(l, 1);
      l += __shfl_xor(l, 2);
      if (sub == 0) { sm[ul] = m; sl[ul] = l; }
    }
  }
  __syncthreads();

  // partial PV: thread = (ug, e); 8-deep manual load pipeline (ILP)
  {
    int e = t & 63, ug = t >> 6;
    const ushort* Vb = QKVb + 1024 + h*HD + ((size_t)(b*L_ + c*CH))*QS;
    float acc[3] = {0.f, 0.f, 0.f};
    for (int kb0 = 0; kb0 < CH; kb0 += 8) {
      float vv[8];
      #pragma unroll
      for (int j = 0; j < 8; j++) vv[j] = b2f(Vb[(size_t)(kb0 + j)*QS + e]);   // 8 loads in flight
      #pragma unroll
      for (int j = 0; j < 8; j++) {
        #pragma unroll
        for (int iu = 0; iu < 3; iu++) {
          int ul = ug + iu*4;
          if (ul < NU) acc[iu] += sc[ul][kb0 + j] * vv[j];   // sc read is wave-uniform broadcast
        }
      }
    }
    #pragma unroll
    for (int iu = 0; iu < 3; iu++) {
      int ul = ug + iu*4;
      if (ul < NU) Pacc[((size_t)chunk*35 + u0 + ul)*64 + e] = acc[iu];
    }
  }
  if (t < NU) { Pm[chunk*35 + u0 + t] = sm[t]; Pl[chunk*35 + u0 + t] = sl[t]; }
}

// ---------------- LayerNorm: bf16 trunk (+ optional bf16 delta) -> bf16 trunk --------
__global__ __launch_bounds__(512) void ln_kernel(const ushort* __restrict__ Xin,
    const ushort* __restrict__ AddB, const float* __restrict__ g, const float* __restrict__ beta,
    ushort* __restrict__ Xout)
{
  int row = blockIdx.x, t = threadIdx.x;
  __shared__ float red[16];
  size_t idx = (size_t)row*DM + t;
  float v = b2f(Xin[idx]);
  if (AddB) v += b2f(AddB[idx]);
  float s = v;
  #pragma unroll
  for (int off = 32; off; off >>= 1) s += __shfl_xor(s, off);
  if ((t & 63) == 0) red[t >> 6] = s;
  __syncthreads();
  float mean = 0.f;
  #pragma unroll
  for (int k = 0; k < 8; k++) mean += red[k];
  mean *= (1.f/DM);
  float d = v - mean, q = d*d;
  #pragma unroll
  for (int off = 32; off; off >>= 1) q += __shfl_xor(q, off);
  if ((t & 63) == 0) red[8 + (t >> 6)] = q;
  __syncthreads();
  float var = 0.f;
  #pragma unroll
  for (int k = 0; k < 8; k++) var += red[8 + k];
  var *= (1.f/DM);
  float r = d / sqrtf(var + 1e-5f) * g[t] + beta[t];
  Xout[idx] = f2b(r);
}

// ---------------- partial mean pool (bf16 trunk) + classifier ----------------
__global__ __launch_bounds__(512) void poolp_kernel(const ushort* __restrict__ Xt, float* __restrict__ pooledP)
{
  int p = blockIdx.x;
  int t = threadIdx.x;
  int b = p >> 3, seg = p & 7;
  float s = 0.f;
  const ushort* base = Xt + ((size_t)b*L_ + seg*128)*DM + t;
  for (int l = 0; l < 128; l++) s += b2f(base[(size_t)l*DM]);
  pooledP[p*DM + t] = s;
}

__global__ __launch_bounds__(64) void cls_kernel(const float* __restrict__ pooledP,
    const float* __restrict__ Wc, const float* __restrict__ bc, float* __restrict__ out)
{
  int o = blockIdx.x;
  int b = o/10, c = o%10, t = threadIdx.x;
  float s = 0.f;
  for (int d = t; d < DM; d += 64) {
    float p = 0.f;
    #pragma unroll
    for (int seg = 0; seg < 8; seg++) p += pooledP[(b*8 + seg)*DM + d];
    s += p * (1.f/L_) * Wc[d*10 + c];
  }
  #pragma unroll
  for (int off = 32; off; off >>= 1) s += __shfl_xor(s, off);
  if (t == 0) out[o] = bc[c] + s;
}

extern "C" void kernel_launch(void* const* d_in, const int* in_sizes, int n_in,
                              void* d_out, int out_size, void* d_ws, size_t ws_size,
                              hipStream_t stream)
{
  const float* src   = (const float*)d_in[0];
  const int*   idxs  = (const int*)d_in[1];
  const float* Wemb  = (const float*)d_in[2];
  const float* bemb  = (const float*)d_in[3];
  const float* Wq    = (const float*)d_in[4];
  const float* bq    = (const float*)d_in[5];
  const float* Wk    = (const float*)d_in[6];
  const float* bk    = (const float*)d_in[7];
  const float* Wv    = (const float*)d_in[8];
  const float* bv    = (const float*)d_in[9];
  const float* Wo    = (const float*)d_in[10];
  const float* bo    = (const float*)d_in[11];
  const float* g1    = (const float*)d_in[12];
  const float* beta1 = (const float*)d_in[13];
  const float* W1    = (const float*)d_in[14];
  const float* bf1   = (const float*)d_in[15];
  const float* W2    = (const float*)d_in[16];
  const float* bf2   = (const float*)d_in[17];
  const float* g2    = (const float*)d_in[18];
  const float* beta2 = (const float*)d_in[19];
  const float* gf    = (const float*)d_in[20];
  const float* betaf = (const float*)d_in[21];
  const float* Wc    = (const float*)d_in[22];
  const float* bc    = (const float*)d_in[23];
  float* out = (float*)d_out;

  float* wsf = (float*)d_ws;
  // attention scratch in [0, 2097152) — Xt is live, this region is attention-phase-only
  float*  Pacc  = wsf;                              // 573,440 fl
  float*  VmeanP = wsf + 573440;                    // 32,768 fl
  float*  D     = wsf + 606208;                     // 71,680 fl (1120*64)
  float*  base  = wsf + 677888;                     // 2,048 fl
  int*    mask  = (int*)(wsf + 679936);             // 4,096 int
  int*    ent   = (int*)(wsf + 684032);             // 32,768 int (ends 716800 < 2097152)
  ushort* Xt    = (ushort*)(wsf + 2097152);         // bf16 trunk: [2097152, 3145728)
  ushort* QKVb  = (ushort*)(wsf + 4194304);         // bf16 QKV: [4194304, 7340032) fl
  ushort* Ob    = (ushort*)(wsf + 7340032);         // bf16 attn-delta out: [7340032, 8388608) fl
  ushort* H     = (ushort*)(wsf + 4194304);         // FFN hidden bf16 (QKVb+Ob dead by FFN1)
  ushort* Yb    = (ushort*)(wsf + 8388608);         // bf16 FFN2 out: [8388608, 9437184) fl
  ushort* Wqkvt = (ushort*)(wsf + 10485760);        // 786,432 fl
  ushort* W1t   = (ushort*)(wsf + 11534336);        // 1,048,576 fl
  ushort* W2t   = (ushort*)(wsf + 12582912);        // 1,048,576 fl
  float*  bqkv  = wsf + 13631488;                   // 3,072
  float*  Msc   = wsf + 13634560;                   // 32,768 (dead after topk)
  float*  Pm    = wsf + 13634560;                   // alias Msc: 8,960
  float*  Pl    = wsf + 13634560 + 8960;            // alias Msc: 8,960
  float*  Vmean = wsf + 13667328;                   // 2,048
  float*  pooledP = wsf + 13669376;                 // 16,384
  int*    idx_top = (int*)(wsf + 13685760);         // 1,120

  // weight conversion: QKV merged (z = which*2+layer); W1/W2 layer-batched; Wo stays f32
  wconv_qkv_kernel<<<dim3(DM/32, DM/32, 6), 256, 0, stream>>>(Wq, Wk, Wv, Wqkvt);
  wconv_kernel<<<dim3(DFF/32, DM/32, 2), 256, 0, stream>>>(W1, W1t, DM, DFF, (size_t)DM*DFF, (size_t)DFF*DM);
  wconv_kernel<<<dim3(DM/32, DFF/32, 2), 256, 0, stream>>>(W2, W2t, DFF, DM, (size_t)DFF*DM, (size_t)DM*DFF);
  bcat_kernel<<<12, 256, 0, stream>>>(bq, bk, bv, bqkv);

  const int M = B_ * L_; // 4096
  embed_kernel<<<M, 512, 0, stream>>>(src, Wemb, bemb, Xt);

  for (int l = 0; l < 2; l++) {
    const size_t vo = (size_t)l*DM;
    const float* Wo_l = Wo + (size_t)l*DM*DM;
    // QKV: [4096,512] x [512,1536] -> bf16 out, 12x32 = 384 blocks (128x128 tiles)
    mfma_gemm<128,128,3><<<dim3(QS/128, M/128), 256, 0, stream>>>(
        Xt, Wqkvt + (size_t)l*QS*DM, bqkv + (size_t)l*QS, nullptr, nullptr, QKVb, M, QS, DM);
    qksample_kernel<<<B_*NH*L_, 64, 0, stream>>>(QKVb, idxs + (size_t)l*L_*KS, Msc);
    topk_kernel<<<B_*NH, 64, 0, stream>>>(Msc, idx_top);
    vmean_part_kernel<<<B_*NH*VSEG, 64, 0, stream>>>(QKVb, VmeanP, mask);
    vmean_merge_kernel<<<B_*NH, 64, 0, stream>>>(VmeanP, Vmean);
    build_map_kernel<<<(B_*NH*KS + 255)/256, 256, 0, stream>>>(idx_top, mask, ent);
    gemv_base_kernel<<<B_, 512, 0, stream>>>(Vmean, Wo_l, bo + vo, base);
    attn_part_kernel<<<B_*NH*NCH*4, 256, 0, stream>>>(QKVb, idx_top, Pacc, Pm, Pl);
    attn_merge_delta_kernel<<<B_*NH, 256, 0, stream>>>(Pacc, Pm, Pl, Vmean, D);
    ob_fill_kernel<<<M, 512, 0, stream>>>(base, D, mask, ent, Wo_l, Ob);
    ln_kernel<<<M, 512, 0, stream>>>(Xt, Ob, g1 + vo, beta1 + vo, Xt);
    // FFN1: [4096,512] x [512,2048] -> gelu bf16, 16x32 = 512 blocks (128x128 tiles)
    mfma_gemm<128,128,1><<<dim3(DFF/128, M/128), 256, 0, stream>>>(
        Xt, W1t + (size_t)l*DFF*DM, bf1 + (size_t)l*DFF, nullptr, nullptr, H, M, DFF, DM);
    // FFN2: [4096,2048] x [2048,512] -> bf16 delta Yb (residual added in ln2)
    mfma_gemm<64,64,3><<<dim3(DM/64, M/64), 256, 0, stream>>>(
        H, W2t + (size_t)l*DM*DFF, bf2 + vo, nullptr, nullptr, Yb, M, DM, DFF);
    ln_kernel<<<M, 512, 0, stream>>>(Xt, Yb, g2 + vo, beta2 + vo, Xt);
  }
  ln_kernel<<<M, 512, 0, stream>>>(Xt, nullptr, gf, betaf, Xt);
  poolp_kernel<<<B_*8, 512, 0, stream>>>(Xt, pooledP);
  cls_kernel<<<40, 64, 0, stream>>>(pooledP, Wc, bc, out);
}

// Round 22
// 392.404 us; speedup vs baseline: 1.1389x; 1.1389x over previous
//
#include <hip/hip_runtime.h>
#include <hip/hip_bf16.h>
#include <math.h>

#define B_ 4
#define L_ 1024
#define DM 512
#define NH 8
#define HD 64
#define DFF 2048
#define KS 35
#define QS 1536   // packed QKV row stride
#define CH 128    // attention key chunk
#define NCH (L_/CH)
#define VSEG 16   // V-mean segments per head

typedef __attribute__((ext_vector_type(8))) short bf16x8;
typedef __attribute__((ext_vector_type(4))) float f32x4;

__device__ inline ushort f2b(float f){
  __hip_bfloat16 h = __float2bfloat16(f);
  return *reinterpret_cast<ushort*>(&h);
}
__device__ inline float b2f(ushort u){
  union { unsigned int i; float f; } x; x.i = ((unsigned int)u) << 16; return x.f;
}
__device__ inline float gelu_exact(float x){
  return 0.5f*x*(1.0f+erff(x*0.7071067811865476f));
}

#define GLOAD16(g, l) __builtin_amdgcn_global_load_lds( \
    (const __attribute__((address_space(1))) void*)(g), \
    (__attribute__((address_space(3))) void*)(l), 16, 0, 0)

// ---------------- weight convert + transpose to bf16 [N][K] (layer-batched) ----------
__global__ __launch_bounds__(256) void wconv_kernel(const float* __restrict__ W,
    ushort* __restrict__ Wt, int K, int N, size_t sStride, size_t dStride)
{
  W  += (size_t)blockIdx.z * sStride;
  Wt += (size_t)blockIdx.z * dStride;
  __shared__ float tile[32][33];
  int n0 = blockIdx.x*32, k0 = blockIdx.y*32;
  int tx = threadIdx.x & 31, ty = threadIdx.x >> 5;
  #pragma unroll
  for (int i = ty; i < 32; i += 8) tile[i][tx] = W[(size_t)(k0+i)*N + n0+tx];
  __syncthreads();
  #pragma unroll
  for (int i = ty; i < 32; i += 8) Wt[(size_t)(n0+i)*K + k0+tx] = f2b(tile[tx][i]);
}

// QKV variant: z in [0,6) = which*2 + layer; one dispatch for all six 512x512 blocks
__global__ __launch_bounds__(256) void wconv_qkv_kernel(const float* __restrict__ Wq,
    const float* __restrict__ Wk, const float* __restrict__ Wv, ushort* __restrict__ Wt)
{
  int z = blockIdx.z, which = z >> 1, l = z & 1;
  const float* W = ((which == 0) ? Wq : (which == 1) ? Wk : Wv) + (size_t)l*DM*DM;
  ushort* dst = Wt + (size_t)l*QS*DM + (size_t)which*512*DM;
  __shared__ float tile[32][33];
  int n0 = blockIdx.x*32, k0 = blockIdx.y*32;
  int tx = threadIdx.x & 31, ty = threadIdx.x >> 5;
  #pragma unroll
  for (int i = ty; i < 32; i += 8) tile[i][tx] = W[(size_t)(k0+i)*DM + n0+tx];
  __syncthreads();
  #pragma unroll
  for (int i = ty; i < 32; i += 8) dst[(size_t)(n0+i)*DM + k0+tx] = f2b(tile[tx][i]);
}

__global__ __launch_bounds__(256) void bcat_kernel(const float* __restrict__ bq,
    const float* __restrict__ bk, const float* __restrict__ bv, float* __restrict__ bqkv)
{
  int i = blockIdx.x*256 + threadIdx.x;   // 0..3071
  if (i >= 2*QS) return;
  int l = i / QS, j = i - l*QS;
  const float* src = (j < 512) ? bq : (j < 1024 ? bk : bv);
  bqkv[i] = src[l*DM + (j & 511)];
}

// ---------------- bf16 MFMA GEMM: dbuf, K=64/tile, COUNTED vmcnt (T4), XCD-swizzled --
// MODE 0: f32 out, 1: gelu->bf16 out, 2: +R f32 out, 3: plain bf16 out
template<int BM, int BN, int MODE>
__global__ __launch_bounds__(256) void mfma_gemm(
    const ushort* __restrict__ A, const ushort* __restrict__ Bt,
    const float* __restrict__ bias, const float* __restrict__ R,
    float* __restrict__ Cf, ushort* __restrict__ Cb,
    int M, int N, int K)
{
  constexpr int MF = BM/32;          // A fragments per wave
  constexpr int NF = BN/32;          // B fragments per wave
  constexpr int AIT = BM*4/256;      // staging iters per K=32 sub-tile
  constexpr int BIT = BN*4/256;
  constexpr int LT = (AIT + BIT)*2;  // gload_lds ops per K=64 tile per thread (4/6/8)
  __shared__ __align__(16) ushort As[2][2][BM*32];
  __shared__ __align__(16) ushort Bs[2][2][BN*32];
  const int t = threadIdx.x, lane = t & 63, w = t >> 6, wr = w >> 1, wc = w & 1;

  // XCD-chunked bijective swizzle (all grids are multiples of 8)
  const int gx = gridDim.x;
  const int nwg = gx * gridDim.y;
  const int bid = blockIdx.y*gx + blockIdx.x;
  const int swz = (bid & 7)*(nwg >> 3) + (bid >> 3);
  const int row0 = (swz / gx)*BM, col0 = (swz % gx)*BN;

  // staging: linear LDS dest, inverse-swizzled global source (per K=32 sub-tile)
  const ushort* aSrc[AIT]; int aDst[AIT];
  #pragma unroll
  for (int j = 0; j < AIT; j++) {
    int ch = j*256 + t, r = ch >> 2, cc = ch & 3, cs = cc ^ ((r >> 1) & 3);
    aSrc[j] = A + (size_t)(row0 + r)*K + cs*8;
    aDst[j] = ch*16;
  }
  const ushort* bSrc[BIT]; int bDst[BIT];
  #pragma unroll
  for (int j = 0; j < BIT; j++) {
    int ch = j*256 + t, r = ch >> 2, cc = ch & 3, cs = cc ^ ((r >> 1) & 3);
    bSrc[j] = Bt + (size_t)(col0 + r)*K + cs*8;
    bDst[j] = ch*16;
  }
  // fragment read offsets (swizzled, within one sub-tile)
  int aOff[MF], bOff[NF];
  #pragma unroll
  for (int m = 0; m < MF; m++) {
    int r = wr*(BM/2) + m*16 + (lane & 15);
    aOff[m] = r*64 + (((lane >> 4)*16) ^ (((r >> 1) & 3) << 4));
  }
  #pragma unroll
  for (int n = 0; n < NF; n++) {
    int r = wc*(BN/2) + n*16 + (lane & 15);
    bOff[n] = r*64 + (((lane >> 4)*16) ^ (((r >> 1) & 3) << 4));
  }
  f32x4 zero = {0.f, 0.f, 0.f, 0.f};
  f32x4 acc[MF][NF];
  #pragma unroll
  for (int m = 0; m < MF; m++)
    #pragma unroll
    for (int n = 0; n < NF; n++) acc[m][n] = zero;

#define STAGE_TILE(kt, buf) do { \
    _Pragma("unroll") \
    for (int j = 0; j < AIT; j++) GLOAD16(aSrc[j] + (kt),      (char*)As[buf][0] + aDst[j]); \
    _Pragma("unroll") \
    for (int j = 0; j < AIT; j++) GLOAD16(aSrc[j] + (kt) + 32, (char*)As[buf][1] + aDst[j]); \
    _Pragma("unroll") \
    for (int j = 0; j < BIT; j++) GLOAD16(bSrc[j] + (kt),      (char*)Bs[buf][0] + bDst[j]); \
    _Pragma("unroll") \
    for (int j = 0; j < BIT; j++) GLOAD16(bSrc[j] + (kt) + 32, (char*)Bs[buf][1] + bDst[j]); \
  } while (0)

  const int nk = K >> 6;             // K/64, always >= 8 here
  // prologue: 2-deep prefetch — T0 -> buf0, T1 -> buf1
  STAGE_TILE(0, 0);
  STAGE_TILE(64, 1);

  for (int ki = 0; ki < nk; ki++) {
    const int cur = ki & 1;
    // wait for tile ki's loads; tile ki+1's LT loads may remain in flight (never 0 mid-loop)
    if (ki + 1 < nk) {
      if constexpr (LT == 8)      asm volatile("s_waitcnt vmcnt(8)" ::: "memory");
      else if constexpr (LT == 6) asm volatile("s_waitcnt vmcnt(6)" ::: "memory");
      else                        asm volatile("s_waitcnt vmcnt(4)" ::: "memory");
    } else {
      asm volatile("s_waitcnt vmcnt(0)" ::: "memory");
    }
    __builtin_amdgcn_sched_barrier(0);
    __builtin_amdgcn_s_barrier();      // all waves have tile ki resident
    #pragma unroll
    for (int s = 0; s < 2; s++) {      // two K=32 sub-steps, same accumulation order
      bf16x8 af[MF], bfr[NF];
      #pragma unroll
      for (int m = 0; m < MF; m++) af[m] = *(const bf16x8*)((const char*)As[cur][s] + aOff[m]);
      #pragma unroll
      for (int n = 0; n < NF; n++) bfr[n] = *(const bf16x8*)((const char*)Bs[cur][s] + bOff[n]);
      #pragma unroll
      for (int m = 0; m < MF; m++)
        #pragma unroll
        for (int n = 0; n < NF; n++)
          acc[m][n] = __builtin_amdgcn_mfma_f32_16x16x32_bf16(af[m], bfr[n], acc[m][n], 0, 0, 0);
    }
    __builtin_amdgcn_s_barrier();      // all waves done reading buf[cur]
    if (ki + 2 < nk) STAGE_TILE((ki + 2) << 6, cur);   // refill the just-read buffer
  }
#undef STAGE_TILE

  #pragma unroll
  for (int m = 0; m < MF; m++) {
    int rb = row0 + wr*(BM/2) + m*16 + ((lane >> 4) << 2);
    #pragma unroll
    for (int n = 0; n < NF; n++) {
      int c = col0 + wc*(BN/2) + n*16 + (lane & 15);
      float bv = bias[c];
      #pragma unroll
      for (int j = 0; j < 4; j++) {
        size_t idx = (size_t)(rb + j)*N + c;
        float v = acc[m][n][j] + bv;
        if (MODE == 1)      Cb[idx] = f2b(gelu_exact(v));
        else if (MODE == 2) Cf[idx] = v + R[idx];
        else if (MODE == 3) Cb[idx] = f2b(v);
        else                Cf[idx] = v;
      }
    }
  }
}

// ---------------- embed + positional encoding (bf16 trunk out) ----------------
__global__ __launch_bounds__(512) void embed_kernel(const float* __restrict__ src,
    const float* __restrict__ Wemb, const float* __restrict__ bemb,
    ushort* __restrict__ Xt)
{
  int row = blockIdx.x, l = row & (L_-1), t = threadIdx.x;
  __shared__ float s_src[32];
  if (t < 32) s_src[t] = src[row*32 + t];
  __syncthreads();
  float acc = bemb[t];
  #pragma unroll
  for (int k = 0; k < 32; k++) acc += s_src[k]*Wemb[k*DM + t];
  int i2 = t & ~1;
  float freq = expf((float)i2 * (-9.210340371976184f/512.0f));
  float ang = (float)l * freq;
  acc += (t & 1) ? cosf(ang) : sinf(ang);
  Xt[(size_t)row*DM + t] = f2b(acc);
}

// ---------------- QK_sample -> M score (bf16 QKV, j-parallel) ----------------
__global__ __launch_bounds__(64) void qksample_kernel(const ushort* __restrict__ QKVb,
    const int* __restrict__ idx_s, float* __restrict__ Msc)
{
  int gid = blockIdx.x;              // (b*8+h)*1024 + i
  int i = gid & (L_-1), h = (gid >> 10) & 7, b = gid >> 13;
  int t = threadIdx.x;
  int j4 = t >> 2, e4 = t & 3;       // lane = j4*4 + e4
  const ushort* Qrow = QKVb + ((size_t)(b*L_ + i))*QS + h*HD + e4*16;
  bf16x8 qa = *(const bf16x8*)(Qrow);
  bf16x8 qb = *(const bf16x8*)(Qrow + 8);
  float q[16];
  #pragma unroll
  for (int x = 0; x < 8; x++) { q[x] = b2f((ushort)qa[x]); q[8+x] = b2f((ushort)qb[x]); }
  const ushort* Kbase = QKVb + 512 + h*HD + (size_t)b*L_*QS + e4*16;
  const int* idq = idx_s + i*KS;
  float mx = -3.4e38f, sm = 0.f;
  #pragma unroll
  for (int p = 0; p < 3; p++) {
    int j = p*16 + j4;
    int jc = (j < KS) ? j : 0;       // inactive lanes redo j=0 (result discarded)
    int s = idq[jc];
    const ushort* Kr = Kbase + (size_t)s*QS;
    bf16x8 ka = *(const bf16x8*)(Kr);
    bf16x8 kb = *(const bf16x8*)(Kr + 8);
    float d = 0.f;
    #pragma unroll
    for (int x = 0; x < 8; x++) d += q[x]   * b2f((ushort)ka[x]);
    #pragma unroll
    for (int x = 0; x < 8; x++) d += q[8+x] * b2f((ushort)kb[x]);
    d += __shfl_xor(d, 1);
    d += __shfl_xor(d, 2);
    if (j < KS && e4 == 0) { mx = fmaxf(mx, d); sm += d; }
  }
  #pragma unroll
  for (int off = 4; off < 64; off <<= 1) {
    mx = fmaxf(mx, __shfl_xor(mx, off));
    sm += __shfl_xor(sm, off);
  }
  if (t == 0) Msc[gid] = mx - sm*(1.0f/KS);
}

// ---------------- register-resident top-35 (tie-break lower index) ----------------
__global__ __launch_bounds__(64) void topk_kernel(const float* __restrict__ Msc, int* __restrict__ idx_top)
{
  int bh = blockIdx.x, t = threadIdx.x;
  float v[16];
  #pragma unroll
  for (int r = 0; r < 16; r++) v[r] = Msc[(size_t)bh*L_ + r*64 + t];
  for (int sel = 0; sel < KS; sel++) {
    float bv = -3.4e38f; int br = 0;
    #pragma unroll
    for (int r = 0; r < 16; r++) {
      bool gt = v[r] > bv;
      bv = gt ? v[r] : bv;
      br = gt ? r : br;
    }
    int bi = br*64 + t;
    #pragma unroll
    for (int off = 32; off; off >>= 1) {
      float ov = __shfl_xor(bv, off); int oi = __shfl_xor(bi, off);
      if (ov > bv || (ov == bv && oi < bi)) { bv = ov; bi = oi; }
    }
    if (t == 0) idx_top[bh*KS + sel] = bi;
    if ((bi & 63) == t) v[bi >> 6] = -3.4e38f;
  }
}

// ---------------- V mean over L: segmented partials + merge (bf16 V) ----------------
__global__ __launch_bounds__(64) void vmean_part_kernel(const ushort* __restrict__ QKVb,
    float* __restrict__ VmeanP)
{
  int gid = blockIdx.x;              // bh*VSEG + seg  (512 blocks)
  int seg = gid & (VSEG-1), bh = gid >> 4;
  int h = bh & 7, b = bh >> 3;
  int e = threadIdx.x;
  const ushort* Vb = QKVb + 1024 + h*HD + ((size_t)(b*L_ + seg*(L_/VSEG)))*QS;
  float s = 0.f;
  for (int l0 = 0; l0 < L_/VSEG; l0 += 8) {
    float vv[8];
    #pragma unroll
    for (int j = 0; j < 8; j++) vv[j] = b2f(Vb[(size_t)(l0+j)*QS + e]);
    #pragma unroll
    for (int j = 0; j < 8; j++) s += vv[j];
  }
  VmeanP[gid*HD + e] = s;
}

__global__ __launch_bounds__(64) void vmean_merge_kernel(const float* __restrict__ VmeanP,
    float* __restrict__ Vmean)
{
  int bh = blockIdx.x, e = threadIdx.x;
  float s = 0.f;
  #pragma unroll
  for (int seg = 0; seg < VSEG; seg++) s += VmeanP[(bh*VSEG + seg)*HD + e];
  Vmean[bh*HD + e] = s * (1.f/L_);
}

// ---------------- fill context with broadcast V-mean (bf16) ----------------
__global__ __launch_bounds__(512) void ctxfill_kernel(const float* __restrict__ Vmean, ushort* __restrict__ CTXb)
{
  int row = blockIdx.x, b = row >> 10, t = threadIdx.x;
  CTXb[(size_t)row*DM + t] = f2b(Vmean[b*DM + t]);
}

// ---------------- chunked flash attention, phase A (bf16 QKV, query-split ×4) ----
// grid: ((b*8+h)*8 + chunk)*4 + q  (1024 blocks), block 256
__global__ __launch_bounds__(256) void attn_part_kernel(const ushort* __restrict__ QKVb,
    const int* __restrict__ idx_top,
    float* __restrict__ Pacc, float* __restrict__ Pm, float* __restrict__ Pl)
{
  int gid = blockIdx.x;
  int q = gid & 3, c = (gid >> 2) & 7, bh = gid >> 5;
  int h = bh & 7, b = bh >> 3;
  int chunk = bh*NCH + c;            // Pacc/Pm/Pl slot (same layout as before)
  int u0 = q*9;
  int NU = (q == 3) ? 8 : 9;
  int t = threadIdx.x;
  __shared__ float qs[9][68];          // scaled Q rows (padded pitch)
  __shared__ float sc[9][132];         // scores -> exp'd scores
  __shared__ float sm[9], sl[9];

  // load + scale this block's Q rows
  for (int idx = t; idx < NU*64; idx += 256) {
    int ul = idx >> 6, e = idx & 63;
    int qi = idx_top[bh*KS + u0 + ul];
    qs[ul][e] = b2f(QKVb[((size_t)(b*L_ + qi))*QS + h*HD + e]) * 0.125f;
  }
  __syncthreads();

  // scores: thread k = t&127 owns one key; K row in 8 bf16x8 regs (convert inline)
  {
    int k = t & 127, par = t >> 7;
    const ushort* Kr = QKVb + ((size_t)(b*L_ + c*CH + k))*QS + 512 + h*HD;
    bf16x8 kreg[8];
    #pragma unroll
    for (int i8 = 0; i8 < 8; i8++) kreg[i8] = *(const bf16x8*)(Kr + i8*8);
    for (int ul = par; ul < NU; ul += 2) {
      float d = 0.f;
      #pragma unroll
      for (int i8 = 0; i8 < 8; i8++) {
        bf16x8 kv = kreg[i8];
        float4 qa = *(const float4*)&qs[ul][i8*8];
        float4 qb = *(const float4*)&qs[ul][i8*8 + 4];
        d += qa.x*b2f((ushort)kv[0]) + qa.y*b2f((ushort)kv[1])
           + qa.z*b2f((ushort)kv[2]) + qa.w*b2f((ushort)kv[3]);
        d += qb.x*b2f((ushort)kv[4]) + qb.y*b2f((ushort)kv[5])
           + qb.z*b2f((ushort)kv[6]) + qb.w*b2f((ushort)kv[7]);
      }
      sc[ul][k] = d;
    }
  }
  __syncthreads();

  // softmax per ul: 4 threads/row
  {
    int ul = t >> 2, sub = t & 3;
    if (ul < NU) {
      float m = -3.4e38f;
      for (int i = sub; i < 128; i += 4) m = fmaxf(m, sc[ul][i]);
      m = fmaxf(m, __shfl_xor(m, 1));
      m = fmaxf(m, __shfl_xor(m, 2));
      float l = 0.f;
      for (int i = sub; i < 128; i += 4) {
        float ev = expf(sc[ul][i] - m);
        sc[ul][i] = ev;
        l += ev;
      }
      l += __shfl_xor(l, 1);
      l += __shfl_xor(l, 2);
      if (sub == 0) { sm[ul] = m; sl[ul] = l; }
    }
  }
  __syncthreads();

  // partial PV: thread = (ug, e); 8-deep manual load pipeline (ILP)
  {
    int e = t & 63, ug = t >> 6;
    const ushort* Vb = QKVb + 1024 + h*HD + ((size_t)(b*L_ + c*CH))*QS;
    float acc[3] = {0.f, 0.f, 0.f};
    for (int kb0 = 0; kb0 < CH; kb0 += 8) {
      float vv[8];
      #pragma unroll
      for (int j = 0; j < 8; j++) vv[j] = b2f(Vb[(size_t)(kb0 + j)*QS + e]);   // 8 loads in flight
      #pragma unroll
      for (int j = 0; j < 8; j++) {
        #pragma unroll
        for (int iu = 0; iu < 3; iu++) {
          int ul = ug + iu*4;
          if (ul < NU) acc[iu] += sc[ul][kb0 + j] * vv[j];   // sc read is wave-uniform broadcast
        }
      }
    }
    #pragma unroll
    for (int iu = 0; iu < 3; iu++) {
      int ul = ug + iu*4;
      if (ul < NU) Pacc[((size_t)chunk*35 + u0 + ul)*64 + e] = acc[iu];
    }
  }
  if (t < NU) { Pm[chunk*35 + u0 + t] = sm[t]; Pl[chunk*35 + u0 + t] = sl[t]; }
}

// ---------------- phase B: merge partials, scatter bf16 ctx ----------------
__global__ __launch_bounds__(256) void attn_merge_kernel(const float* __restrict__ Pacc,
    const float* __restrict__ Pm, const float* __restrict__ Pl,
    const int* __restrict__ idx_top, ushort* __restrict__ CTXb)
{
  int bh = blockIdx.x;
  int h = bh & 7, b = bh >> 3;
  int t = threadIdx.x;
  __shared__ float m8[NCH*35], l8[NCH*35];
  for (int i = t; i < NCH*35; i += 256) {
    int c = i / 35, u = i - c*35;
    m8[c*35 + u] = Pm[((size_t)bh*NCH + c)*35 + u];
    l8[c*35 + u] = Pl[((size_t)bh*NCH + c)*35 + u];
  }
  __syncthreads();
  int e = t & 63, ug = t >> 6;
  #pragma unroll
  for (int iu = 0; iu < 9; iu++) {
    int u = ug + iu*4;
    if (u >= 35) break;
    float M = -3.4e38f;
    #pragma unroll
    for (int c = 0; c < NCH; c++) M = fmaxf(M, m8[c*35 + u]);
    float Ltot = 0.f, o = 0.f;
    #pragma unroll
    for (int c = 0; c < NCH; c++) {
      float w = expf(m8[c*35 + u] - M);
      Ltot += w * l8[c*35 + u];
      o += w * Pacc[(((size_t)bh*NCH + c)*35 + u)*64 + e];
    }
    int qi = idx_top[bh*KS + u];
    CTXb[((size_t)(b*L_ + qi))*DM + h*HD + e] = f2b(o / Ltot);
  }
}

// ---------------- LayerNorm: bf16 trunk (+ optional bf16 delta) -> bf16 trunk --------
__global__ __launch_bounds__(512) void ln_kernel(const ushort* __restrict__ Xin,
    const ushort* __restrict__ AddB, const float* __restrict__ g, const float* __restrict__ beta,
    ushort* __restrict__ Xout)
{
  int row = blockIdx.x, t = threadIdx.x;
  __shared__ float red[16];
  size_t idx = (size_t)row*DM + t;
  float v = b2f(Xin[idx]);
  if (AddB) v += b2f(AddB[idx]);
  float s = v;
  #pragma unroll
  for (int off = 32; off; off >>= 1) s += __shfl_xor(s, off);
  if ((t & 63) == 0) red[t >> 6] = s;
  __syncthreads();
  float mean = 0.f;
  #pragma unroll
  for (int k = 0; k < 8; k++) mean += red[k];
  mean *= (1.f/DM);
  float d = v - mean, q = d*d;
  #pragma unroll
  for (int off = 32; off; off >>= 1) q += __shfl_xor(q, off);
  if ((t & 63) == 0) red[8 + (t >> 6)] = q;
  __syncthreads();
  float var = 0.f;
  #pragma unroll
  for (int k = 0; k < 8; k++) var += red[8 + k];
  var *= (1.f/DM);
  float r = d / sqrtf(var + 1e-5f) * g[t] + beta[t];
  Xout[idx] = f2b(r);
}

// ---------------- partial mean pool (bf16 trunk) + classifier ----------------
__global__ __launch_bounds__(512) void poolp_kernel(const ushort* __restrict__ Xt, float* __restrict__ pooledP)
{
  int p = blockIdx.x;
  int t = threadIdx.x;
  int b = p >> 3, seg = p & 7;
  float s = 0.f;
  const ushort* base = Xt + ((size_t)b*L_ + seg*128)*DM + t;
  for (int l = 0; l < 128; l++) s += b2f(base[(size_t)l*DM]);
  pooledP[p*DM + t] = s;
}

__global__ __launch_bounds__(64) void cls_kernel(const float* __restrict__ pooledP,
    const float* __restrict__ Wc, const float* __restrict__ bc, float* __restrict__ out)
{
  int o = blockIdx.x;
  int b = o/10, c = o%10, t = threadIdx.x;
  float s = 0.f;
  for (int d = t; d < DM; d += 64) {
    float p = 0.f;
    #pragma unroll
    for (int seg = 0; seg < 8; seg++) p += pooledP[(b*8 + seg)*DM + d];
    s += p * (1.f/L_) * Wc[d*10 + c];
  }
  #pragma unroll
  for (int off = 32; off; off >>= 1) s += __shfl_xor(s, off);
  if (t == 0) out[o] = bc[c] + s;
}

extern "C" void kernel_launch(void* const* d_in, const int* in_sizes, int n_in,
                              void* d_out, int out_size, void* d_ws, size_t ws_size,
                              hipStream_t stream)
{
  const float* src   = (const float*)d_in[0];
  const int*   idxs  = (const int*)d_in[1];
  const float* Wemb  = (const float*)d_in[2];
  const float* bemb  = (const float*)d_in[3];
  const float* Wq    = (const float*)d_in[4];
  const float* bq    = (const float*)d_in[5];
  const float* Wk    = (const float*)d_in[6];
  const float* bk    = (const float*)d_in[7];
  const float* Wv    = (const float*)d_in[8];
  const float* bv    = (const float*)d_in[9];
  const float* Wo    = (const float*)d_in[10];
  const float* bo    = (const float*)d_in[11];
  const float* g1    = (const float*)d_in[12];
  const float* beta1 = (const float*)d_in[13];
  const float* W1    = (const float*)d_in[14];
  const float* bf1   = (const float*)d_in[15];
  const float* W2    = (const float*)d_in[16];
  const float* bf2   = (const float*)d_in[17];
  const float* g2    = (const float*)d_in[18];
  const float* beta2 = (const float*)d_in[19];
  const float* gf    = (const float*)d_in[20];
  const float* betaf = (const float*)d_in[21];
  const float* Wc    = (const float*)d_in[22];
  const float* bc    = (const float*)d_in[23];
  float* out = (float*)d_out;

  float* wsf = (float*)d_ws;
  // attention scratch in the freed f32-X region [0, 2097152) — Xt is LIVE during attention now
  float*  Pacc  = wsf;                              // 573,440 fl
  float*  VmeanP = wsf + 573440;                    // 32,768 fl (ends 606208 < 2097152)
  ushort* Xt    = (ushort*)(wsf + 2097152);         // bf16 trunk: [2097152, 3145728)
  ushort* CTXb  = (ushort*)(wsf + 3145728);         // [3145728, 4194304)
  ushort* QKVb  = (ushort*)(wsf + 4194304);         // bf16 QKV: [4194304, 7340032) fl
  ushort* Ob    = (ushort*)(wsf + 7340032);         // bf16 Wo out: [7340032, 8388608) fl
  ushort* H     = (ushort*)(wsf + 4194304);         // FFN hidden bf16 (QKVb+Ob dead by FFN1)
  ushort* Yb    = (ushort*)(wsf + 8388608);         // bf16 FFN2 out: [8388608, 9437184) fl
  ushort* Wqkvt = (ushort*)(wsf + 10485760);        // 786,432 fl
  ushort* Wot   = (ushort*)(wsf + 11272192);        // 262,144 fl
  ushort* W1t   = (ushort*)(wsf + 11534336);        // 1,048,576 fl
  ushort* W2t   = (ushort*)(wsf + 12582912);        // 1,048,576 fl
  float*  bqkv  = wsf + 13631488;                   // 3,072
  float*  Msc   = wsf + 13634560;                   // 32,768 (dead after topk)
  float*  Pm    = wsf + 13634560;                   // alias Msc: 8,960
  float*  Pl    = wsf + 13634560 + 8960;            // alias Msc: 8,960
  float*  Vmean = wsf + 13667328;                   // 2,048
  float*  pooledP = wsf + 13669376;                 // 16,384
  int*    idx_top = (int*)(wsf + 13685760);         // 1,120

  // weight conversion: QKV merged (z = which*2+layer), others layer-batched
  wconv_qkv_kernel<<<dim3(DM/32, DM/32, 6), 256, 0, stream>>>(Wq, Wk, Wv, Wqkvt);
  wconv_kernel<<<dim3(DM/32, DM/32, 2), 256, 0, stream>>>(Wo, Wot, DM, DM, (size_t)DM*DM, (size_t)DM*DM);
  wconv_kernel<<<dim3(DFF/32, DM/32, 2), 256, 0, stream>>>(W1, W1t, DM, DFF, (size_t)DM*DFF, (size_t)DFF*DM);
  wconv_kernel<<<dim3(DM/32, DFF/32, 2), 256, 0, stream>>>(W2, W2t, DFF, DM, (size_t)DFF*DM, (size_t)DM*DFF);
  bcat_kernel<<<12, 256, 0, stream>>>(bq, bk, bv, bqkv);

  const int M = B_ * L_; // 4096
  embed_kernel<<<M, 512, 0, stream>>>(src, Wemb, bemb, Xt);

  for (int l = 0; l < 2; l++) {
    const size_t vo = (size_t)l*DM;
    // QKV: [4096,512] x [512,1536] -> bf16 out, 12x32 = 384 blocks (128x128 tiles)
    mfma_gemm<128,128,3><<<dim3(QS/128, M/128), 256, 0, stream>>>(
        Xt, Wqkvt + (size_t)l*QS*DM, bqkv + (size_t)l*QS, nullptr, nullptr, QKVb, M, QS, DM);
    qksample_kernel<<<B_*NH*L_, 64, 0, stream>>>(QKVb, idxs + (size_t)l*L_*KS, Msc);
    topk_kernel<<<B_*NH, 64, 0, stream>>>(Msc, idx_top);
    vmean_part_kernel<<<B_*NH*VSEG, 64, 0, stream>>>(QKVb, VmeanP);
    vmean_merge_kernel<<<B_*NH, 64, 0, stream>>>(VmeanP, Vmean);
    ctxfill_kernel<<<M, 512, 0, stream>>>(Vmean, CTXb);
    attn_part_kernel<<<B_*NH*NCH*4, 256, 0, stream>>>(QKVb, idx_top, Pacc, Pm, Pl);
    attn_merge_kernel<<<B_*NH, 256, 0, stream>>>(Pacc, Pm, Pl, idx_top, CTXb);
    // Wo: [4096,512] x [512,512] -> bf16 delta Ob (residual added in ln1)
    mfma_gemm<64,64,3><<<dim3(DM/64, M/64), 256, 0, stream>>>(
        CTXb, Wot + (size_t)l*DM*DM, bo + vo, nullptr, nullptr, Ob, M, DM, DM);
    ln_kernel<<<M, 512, 0, stream>>>(Xt, Ob, g1 + vo, beta1 + vo, Xt);
    // FFN1: [4096,512] x [512,2048] -> gelu bf16, 16x32 = 512 blocks (128x128 tiles)
    mfma_gemm<128,128,1><<<dim3(DFF/128, M/128), 256, 0, stream>>>(
        Xt, W1t + (size_t)l*DFF*DM, bf1 + (size_t)l*DFF, nullptr, nullptr, H, M, DFF, DM);
    // FFN2: [4096,2048] x [2048,512] -> bf16 delta Yb (residual added in ln2)
    mfma_gemm<64,64,3><<<dim3(DM/64, M/64), 256, 0, stream>>>(
        H, W2t + (size_t)l*DM*DFF, bf2 + vo, nullptr, nullptr, Yb, M, DM, DFF);
    ln_kernel<<<M, 512, 0, stream>>>(Xt, Yb, g2 + vo, beta2 + vo, Xt);
  }
  ln_kernel<<<M, 512, 0, stream>>>(Xt, nullptr, gf, betaf, Xt);
  poolp_kernel<<<B_*8, 512, 0, stream>>>(Xt, pooledP);
  cls_kernel<<<40, 64, 0, stream>>>(pooledP, Wc, bc, out);
}

// Round 23
// 367.441 us; speedup vs baseline: 1.2162x; 1.0679x over previous
//
#include <hip/hip_runtime.h>
#include <hip/hip_bf16.h>
#include <math.h>

#define B_ 4
#define L_ 1024
#define DM 512
#define NH 8
#define HD 64
#define DFF 2048
#define KS 35
#define QS 1536   // packed QKV row stride
#define CH 128    // attention key chunk
#define NCH (L_/CH)
#define VSEG 16   // V-mean segments per head

typedef __attribute__((ext_vector_type(8))) short bf16x8;
typedef __attribute__((ext_vector_type(4))) float f32x4;

__device__ inline ushort f2b(float f){
  __hip_bfloat16 h = __float2bfloat16(f);
  return *reinterpret_cast<ushort*>(&h);
}
__device__ inline float b2f(ushort u){
  union { unsigned int i; float f; } x; x.i = ((unsigned int)u) << 16; return x.f;
}
__device__ inline float gelu_exact(float x){
  return 0.5f*x*(1.0f+erff(x*0.7071067811865476f));
}

#define GLOAD16(g, l) __builtin_amdgcn_global_load_lds( \
    (const __attribute__((address_space(1))) void*)(g), \
    (__attribute__((address_space(3))) void*)(l), 16, 0, 0)

// ---------------- weight convert + transpose to bf16 [N][K] (layer-batched) ----------
__global__ __launch_bounds__(256) void wconv_kernel(const float* __restrict__ W,
    ushort* __restrict__ Wt, int K, int N, size_t sStride, size_t dStride)
{
  W  += (size_t)blockIdx.z * sStride;
  Wt += (size_t)blockIdx.z * dStride;
  __shared__ float tile[32][33];
  int n0 = blockIdx.x*32, k0 = blockIdx.y*32;
  int tx = threadIdx.x & 31, ty = threadIdx.x >> 5;
  #pragma unroll
  for (int i = ty; i < 32; i += 8) tile[i][tx] = W[(size_t)(k0+i)*N + n0+tx];
  __syncthreads();
  #pragma unroll
  for (int i = ty; i < 32; i += 8) Wt[(size_t)(n0+i)*K + k0+tx] = f2b(tile[tx][i]);
}

// QKV variant: z in [0,6) = which*2 + layer; one dispatch for all six 512x512 blocks
__global__ __launch_bounds__(256) void wconv_qkv_kernel(const float* __restrict__ Wq,
    const float* __restrict__ Wk, const float* __restrict__ Wv, ushort* __restrict__ Wt)
{
  int z = blockIdx.z, which = z >> 1, l = z & 1;
  const float* W = ((which == 0) ? Wq : (which == 1) ? Wk : Wv) + (size_t)l*DM*DM;
  ushort* dst = Wt + (size_t)l*QS*DM + (size_t)which*512*DM;
  __shared__ float tile[32][33];
  int n0 = blockIdx.x*32, k0 = blockIdx.y*32;
  int tx = threadIdx.x & 31, ty = threadIdx.x >> 5;
  #pragma unroll
  for (int i = ty; i < 32; i += 8) tile[i][tx] = W[(size_t)(k0+i)*DM + n0+tx];
  __syncthreads();
  #pragma unroll
  for (int i = ty; i < 32; i += 8) dst[(size_t)(n0+i)*DM + k0+tx] = f2b(tile[tx][i]);
}

__global__ __launch_bounds__(256) void bcat_kernel(const float* __restrict__ bq,
    const float* __restrict__ bk, const float* __restrict__ bv, float* __restrict__ bqkv)
{
  int i = blockIdx.x*256 + threadIdx.x;   // 0..3071
  if (i >= 2*QS) return;
  int l = i / QS, j = i - l*QS;
  const float* src = (j < 512) ? bq : (j < 1024 ? bk : bv);
  bqkv[i] = src[l*DM + (j & 511)];
}

// ---------------- bf16 MFMA GEMM: dbuf, K=64/tile, COUNTED vmcnt (T4), XCD-swizzled --
// MODE 0: f32 out, 1: gelu->bf16 out, 2: +R f32 out, 3: plain bf16 out
template<int BM, int BN, int MODE>
__global__ __launch_bounds__(256) void mfma_gemm(
    const ushort* __restrict__ A, const ushort* __restrict__ Bt,
    const float* __restrict__ bias, const float* __restrict__ R,
    float* __restrict__ Cf, ushort* __restrict__ Cb,
    int M, int N, int K)
{
  constexpr int MF = BM/32;          // A fragments per wave
  constexpr int NF = BN/32;          // B fragments per wave
  constexpr int AIT = BM*4/256;      // staging iters per K=32 sub-tile
  constexpr int BIT = BN*4/256;
  constexpr int LT = (AIT + BIT)*2;  // gload_lds ops per K=64 tile per thread (4/6/8)
  __shared__ __align__(16) ushort As[2][2][BM*32];
  __shared__ __align__(16) ushort Bs[2][2][BN*32];
  const int t = threadIdx.x, lane = t & 63, w = t >> 6, wr = w >> 1, wc = w & 1;

  // XCD-chunked bijective swizzle (all grids are multiples of 8)
  const int gx = gridDim.x;
  const int nwg = gx * gridDim.y;
  const int bid = blockIdx.y*gx + blockIdx.x;
  const int swz = (bid & 7)*(nwg >> 3) + (bid >> 3);
  const int row0 = (swz / gx)*BM, col0 = (swz % gx)*BN;

  // staging: linear LDS dest, inverse-swizzled global source (per K=32 sub-tile)
  const ushort* aSrc[AIT]; int aDst[AIT];
  #pragma unroll
  for (int j = 0; j < AIT; j++) {
    int ch = j*256 + t, r = ch >> 2, cc = ch & 3, cs = cc ^ ((r >> 1) & 3);
    aSrc[j] = A + (size_t)(row0 + r)*K + cs*8;
    aDst[j] = ch*16;
  }
  const ushort* bSrc[BIT]; int bDst[BIT];
  #pragma unroll
  for (int j = 0; j < BIT; j++) {
    int ch = j*256 + t, r = ch >> 2, cc = ch & 3, cs = cc ^ ((r >> 1) & 3);
    bSrc[j] = Bt + (size_t)(col0 + r)*K + cs*8;
    bDst[j] = ch*16;
  }
  // fragment read offsets (swizzled, within one sub-tile)
  int aOff[MF], bOff[NF];
  #pragma unroll
  for (int m = 0; m < MF; m++) {
    int r = wr*(BM/2) + m*16 + (lane & 15);
    aOff[m] = r*64 + (((lane >> 4)*16) ^ (((r >> 1) & 3) << 4));
  }
  #pragma unroll
  for (int n = 0; n < NF; n++) {
    int r = wc*(BN/2) + n*16 + (lane & 15);
    bOff[n] = r*64 + (((lane >> 4)*16) ^ (((r >> 1) & 3) << 4));
  }
  f32x4 zero = {0.f, 0.f, 0.f, 0.f};
  f32x4 acc[MF][NF];
  #pragma unroll
  for (int m = 0; m < MF; m++)
    #pragma unroll
    for (int n = 0; n < NF; n++) acc[m][n] = zero;

#define STAGE_TILE(kt, buf) do { \
    _Pragma("unroll") \
    for (int j = 0; j < AIT; j++) GLOAD16(aSrc[j] + (kt),      (char*)As[buf][0] + aDst[j]); \
    _Pragma("unroll") \
    for (int j = 0; j < AIT; j++) GLOAD16(aSrc[j] + (kt) + 32, (char*)As[buf][1] + aDst[j]); \
    _Pragma("unroll") \
    for (int j = 0; j < BIT; j++) GLOAD16(bSrc[j] + (kt),      (char*)Bs[buf][0] + bDst[j]); \
    _Pragma("unroll") \
    for (int j = 0; j < BIT; j++) GLOAD16(bSrc[j] + (kt) + 32, (char*)Bs[buf][1] + bDst[j]); \
  } while (0)

  const int nk = K >> 6;             // K/64, always >= 8 here
  // prologue: 2-deep prefetch — T0 -> buf0, T1 -> buf1
  STAGE_TILE(0, 0);
  STAGE_TILE(64, 1);

  for (int ki = 0; ki < nk; ki++) {
    const int cur = ki & 1;
    // wait for tile ki's loads; tile ki+1's LT loads may remain in flight (never 0 mid-loop)
    if (ki + 1 < nk) {
      if constexpr (LT == 8)      asm volatile("s_waitcnt vmcnt(8)" ::: "memory");
      else if constexpr (LT == 6) asm volatile("s_waitcnt vmcnt(6)" ::: "memory");
      else                        asm volatile("s_waitcnt vmcnt(4)" ::: "memory");
    } else {
      asm volatile("s_waitcnt vmcnt(0)" ::: "memory");
    }
    __builtin_amdgcn_sched_barrier(0);
    __builtin_amdgcn_s_barrier();      // all waves have tile ki resident
    #pragma unroll
    for (int s = 0; s < 2; s++) {      // two K=32 sub-steps, same accumulation order
      bf16x8 af[MF], bfr[NF];
      #pragma unroll
      for (int m = 0; m < MF; m++) af[m] = *(const bf16x8*)((const char*)As[cur][s] + aOff[m]);
      #pragma unroll
      for (int n = 0; n < NF; n++) bfr[n] = *(const bf16x8*)((const char*)Bs[cur][s] + bOff[n]);
      #pragma unroll
      for (int m = 0; m < MF; m++)
        #pragma unroll
        for (int n = 0; n < NF; n++)
          acc[m][n] = __builtin_amdgcn_mfma_f32_16x16x32_bf16(af[m], bfr[n], acc[m][n], 0, 0, 0);
    }
    __builtin_amdgcn_s_barrier();      // all waves done reading buf[cur]
    if (ki + 2 < nk) STAGE_TILE((ki + 2) << 6, cur);   // refill the just-read buffer
  }
#undef STAGE_TILE

  #pragma unroll
  for (int m = 0; m < MF; m++) {
    int rb = row0 + wr*(BM/2) + m*16 + ((lane >> 4) << 2);
    #pragma unroll
    for (int n = 0; n < NF; n++) {
      int c = col0 + wc*(BN/2) + n*16 + (lane & 15);
      float bv = bias[c];
      #pragma unroll
      for (int j = 0; j < 4; j++) {
        size_t idx = (size_t)(rb + j)*N + c;
        float v = acc[m][n][j] + bv;
        if (MODE == 1)      Cb[idx] = f2b(gelu_exact(v));
        else if (MODE == 2) Cf[idx] = v + R[idx];
        else if (MODE == 3) Cb[idx] = f2b(v);
        else                Cf[idx] = v;
      }
    }
  }
}

// ---------------- embed + positional encoding (bf16 trunk out) ----------------
__global__ __launch_bounds__(512) void embed_kernel(const float* __restrict__ src,
    const float* __restrict__ Wemb, const float* __restrict__ bemb,
    ushort* __restrict__ Xt)
{
  int row = blockIdx.x, l = row & (L_-1), t = threadIdx.x;
  __shared__ float s_src[32];
  if (t < 32) s_src[t] = src[row*32 + t];
  __syncthreads();
  float acc = bemb[t];
  #pragma unroll
  for (int k = 0; k < 32; k++) acc += s_src[k]*Wemb[k*DM + t];
  int i2 = t & ~1;
  float freq = expf((float)i2 * (-9.210340371976184f/512.0f));
  float ang = (float)l * freq;
  acc += (t & 1) ? cosf(ang) : sinf(ang);
  Xt[(size_t)row*DM + t] = f2b(acc);
}

// ---------------- QK_sample -> M score (bf16 QKV, j-parallel) ----------------
__global__ __launch_bounds__(64) void qksample_kernel(const ushort* __restrict__ QKVb,
    const int* __restrict__ idx_s, float* __restrict__ Msc)
{
  int gid = blockIdx.x;              // (b*8+h)*1024 + i
  int i = gid & (L_-1), h = (gid >> 10) & 7, b = gid >> 13;
  int t = threadIdx.x;
  int j4 = t >> 2, e4 = t & 3;       // lane = j4*4 + e4
  const ushort* Qrow = QKVb + ((size_t)(b*L_ + i))*QS + h*HD + e4*16;
  bf16x8 qa = *(const bf16x8*)(Qrow);
  bf16x8 qb = *(const bf16x8*)(Qrow + 8);
  float q[16];
  #pragma unroll
  for (int x = 0; x < 8; x++) { q[x] = b2f((ushort)qa[x]); q[8+x] = b2f((ushort)qb[x]); }
  const ushort* Kbase = QKVb + 512 + h*HD + (size_t)b*L_*QS + e4*16;
  const int* idq = idx_s + i*KS;
  float mx = -3.4e38f, sm = 0.f;
  #pragma unroll
  for (int p = 0; p < 3; p++) {
    int j = p*16 + j4;
    int jc = (j < KS) ? j : 0;       // inactive lanes redo j=0 (result discarded)
    int s = idq[jc];
    const ushort* Kr = Kbase + (size_t)s*QS;
    bf16x8 ka = *(const bf16x8*)(Kr);
    bf16x8 kb = *(const bf16x8*)(Kr + 8);
    float d = 0.f;
    #pragma unroll
    for (int x = 0; x < 8; x++) d += q[x]   * b2f((ushort)ka[x]);
    #pragma unroll
    for (int x = 0; x < 8; x++) d += q[8+x] * b2f((ushort)kb[x]);
    d += __shfl_xor(d, 1);
    d += __shfl_xor(d, 2);
    if (j < KS && e4 == 0) { mx = fmaxf(mx, d); sm += d; }
  }
  #pragma unroll
  for (int off = 4; off < 64; off <<= 1) {
    mx = fmaxf(mx, __shfl_xor(mx, off));
    sm += __shfl_xor(sm, off);
  }
  if (t == 0) Msc[gid] = mx - sm*(1.0f/KS);
}

// ---------------- register-resident top-35 (tie-break lower index) ----------------
__global__ __launch_bounds__(64) void topk_kernel(const float* __restrict__ Msc, int* __restrict__ idx_top)
{
  int bh = blockIdx.x, t = threadIdx.x;
  float v[16];
  #pragma unroll
  for (int r = 0; r < 16; r++) v[r] = Msc[(size_t)bh*L_ + r*64 + t];
  for (int sel = 0; sel < KS; sel++) {
    float bv = -3.4e38f; int br = 0;
    #pragma unroll
    for (int r = 0; r < 16; r++) {
      bool gt = v[r] > bv;
      bv = gt ? v[r] : bv;
      br = gt ? r : br;
    }
    int bi = br*64 + t;
    #pragma unroll
    for (int off = 32; off; off >>= 1) {
      float ov = __shfl_xor(bv, off); int oi = __shfl_xor(bi, off);
      if (ov > bv || (ov == bv && oi < bi)) { bv = ov; bi = oi; }
    }
    if (t == 0) idx_top[bh*KS + sel] = bi;
    if ((bi & 63) == t) v[bi >> 6] = -3.4e38f;
  }
}

// ---------------- V mean over L: segmented partials + merge (bf16 V) ----------------
__global__ __launch_bounds__(64) void vmean_part_kernel(const ushort* __restrict__ QKVb,
    float* __restrict__ VmeanP)
{
  int gid = blockIdx.x;              // bh*VSEG + seg  (512 blocks)
  int seg = gid & (VSEG-1), bh = gid >> 4;
  int h = bh & 7, b = bh >> 3;
  int e = threadIdx.x;
  const ushort* Vb = QKVb + 1024 + h*HD + ((size_t)(b*L_ + seg*(L_/VSEG)))*QS;
  float s = 0.f;
  for (int l0 = 0; l0 < L_/VSEG; l0 += 8) {
    float vv[8];
    #pragma unroll
    for (int j = 0; j < 8; j++) vv[j] = b2f(Vb[(size_t)(l0+j)*QS + e]);
    #pragma unroll
    for (int j = 0; j < 8; j++) s += vv[j];
  }
  VmeanP[gid*HD + e] = s;
}

__global__ __launch_bounds__(64) void vmean_merge_kernel(const float* __restrict__ VmeanP,
    float* __restrict__ Vmean)
{
  int bh = blockIdx.x, e = threadIdx.x;
  float s = 0.f;
  #pragma unroll
  for (int seg = 0; seg < VSEG; seg++) s += VmeanP[(bh*VSEG + seg)*HD + e];
  Vmean[bh*HD + e] = s * (1.f/L_);
}

// ---------------- fill context with broadcast V-mean (bf16) ----------------
__global__ __launch_bounds__(512) void ctxfill_kernel(const float* __restrict__ Vmean, ushort* __restrict__ CTXb)
{
  int row = blockIdx.x, b = row >> 10, t = threadIdx.x;
  CTXb[(size_t)row*DM + t] = f2b(Vmean[b*DM + t]);
}

// ---------------- chunked flash attention, phase A (bf16 QKV, query-split ×4) ----
// grid: ((b*8+h)*8 + chunk)*4 + q  (1024 blocks), block 256
__global__ __launch_bounds__(256) void attn_part_kernel(const ushort* __restrict__ QKVb,
    const int* __restrict__ idx_top,
    float* __restrict__ Pacc, float* __restrict__ Pm, float* __restrict__ Pl)
{
  int gid = blockIdx.x;
  int q = gid & 3, c = (gid >> 2) & 7, bh = gid >> 5;
  int h = bh & 7, b = bh >> 3;
  int chunk = bh*NCH + c;            // Pacc/Pm/Pl slot (same layout as before)
  int u0 = q*9;
  int NU = (q == 3) ? 8 : 9;
  int t = threadIdx.x;
  __shared__ float qs[9][68];          // scaled Q rows (padded pitch)
  __shared__ float sc[9][132];         // scores -> exp'd scores
  __shared__ float sm[9], sl[9];

  // load + scale this block's Q rows
  for (int idx = t; idx < NU*64; idx += 256) {
    int ul = idx >> 6, e = idx & 63;
    int qi = idx_top[bh*KS + u0 + ul];
    qs[ul][e] = b2f(QKVb[((size_t)(b*L_ + qi))*QS + h*HD + e]) * 0.125f;
  }
  __syncthreads();

  // scores: thread k = t&127 owns one key; K row in 8 bf16x8 regs (convert inline)
  {
    int k = t & 127, par = t >> 7;
    const ushort* Kr = QKVb + ((size_t)(b*L_ + c*CH + k))*QS + 512 + h*HD;
    bf16x8 kreg[8];
    #pragma unroll
    for (int i8 = 0; i8 < 8; i8++) kreg[i8] = *(const bf16x8*)(Kr + i8*8);
    for (int ul = par; ul < NU; ul += 2) {
      float d = 0.f;
      #pragma unroll
      for (int i8 = 0; i8 < 8; i8++) {
        bf16x8 kv = kreg[i8];
        float4 qa = *(const float4*)&qs[ul][i8*8];
        float4 qb = *(const float4*)&qs[ul][i8*8 + 4];
        d += qa.x*b2f((ushort)kv[0]) + qa.y*b2f((ushort)kv[1])
           + qa.z*b2f((ushort)kv[2]) + qa.w*b2f((ushort)kv[3]);
        d += qb.x*b2f((ushort)kv[4]) + qb.y*b2f((ushort)kv[5])
           + qb.z*b2f((ushort)kv[6]) + qb.w*b2f((ushort)kv[7]);
      }
      sc[ul][k] = d;
    }
  }
  __syncthreads();

  // softmax per ul: 4 threads/row
  {
    int ul = t >> 2, sub = t & 3;
    if (ul < NU) {
      float m = -3.4e38f;
      for (int i = sub; i < 128; i += 4) m = fmaxf(m, sc[ul][i]);
      m = fmaxf(m, __shfl_xor(m, 1));
      m = fmaxf(m, __shfl_xor(m, 2));
      float l = 0.f;
      for (int i = sub; i < 128; i += 4) {
        float ev = expf(sc[ul][i] - m);
        sc[ul][i] = ev;
        l += ev;
      }
      l += __shfl_xor(l, 1);
      l += __shfl_xor(l, 2);
      if (sub == 0) { sm[ul] = m; sl[ul] = l; }
    }
  }
  __syncthreads();

  // partial PV: thread = (ug, e); 8-deep manual load pipeline (ILP)
  {
    int e = t & 63, ug = t >> 6;
    const ushort* Vb = QKVb + 1024 + h*HD + ((size_t)(b*L_ + c*CH))*QS;
    float acc[3] = {0.f, 0.f, 0.f};
    for (int kb0 = 0; kb0 < CH; kb0 += 8) {
      float vv[8];
      #pragma unroll
      for (int j = 0; j < 8; j++) vv[j] = b2f(Vb[(size_t)(kb0 + j)*QS + e]);   // 8 loads in flight
      #pragma unroll
      for (int j = 0; j < 8; j++) {
        #pragma unroll
        for (int iu = 0; iu < 3; iu++) {
          int ul = ug + iu*4;
          if (ul < NU) acc[iu] += sc[ul][kb0 + j] * vv[j];   // sc read is wave-uniform broadcast
        }
      }
    }
    #pragma unroll
    for (int iu = 0; iu < 3; iu++) {
      int ul = ug + iu*4;
      if (ul < NU) Pacc[((size_t)chunk*35 + u0 + ul)*64 + e] = acc[iu];
    }
  }
  if (t < NU) { Pm[chunk*35 + u0 + t] = sm[t]; Pl[chunk*35 + u0 + t] = sl[t]; }
}

// ---------------- phase B: merge partials, scatter bf16 ctx ----------------
__global__ __launch_bounds__(256) void attn_merge_kernel(const float* __restrict__ Pacc,
    const float* __restrict__ Pm, const float* __restrict__ Pl,
    const int* __restrict__ idx_top, ushort* __restrict__ CTXb)
{
  int bh = blockIdx.x;
  int h = bh & 7, b = bh >> 3;
  int t = threadIdx.x;
  __shared__ float m8[NCH*35], l8[NCH*35];
  for (int i = t; i < NCH*35; i += 256) {
    int c = i / 35, u = i - c*35;
    m8[c*35 + u] = Pm[((size_t)bh*NCH + c)*35 + u];
    l8[c*35 + u] = Pl[((size_t)bh*NCH + c)*35 + u];
  }
  __syncthreads();
  int e = t & 63, ug = t >> 6;
  #pragma unroll
  for (int iu = 0; iu < 9; iu++) {
    int u = ug + iu*4;
    if (u >= 35) break;
    float M = -3.4e38f;
    #pragma unroll
    for (int c = 0; c < NCH; c++) M = fmaxf(M, m8[c*35 + u]);
    float Ltot = 0.f, o = 0.f;
    #pragma unroll
    for (int c = 0; c < NCH; c++) {
      float w = expf(m8[c*35 + u] - M);
      Ltot += w * l8[c*35 + u];
      o += w * Pacc[(((size_t)bh*NCH + c)*35 + u)*64 + e];
    }
    int qi = idx_top[bh*KS + u];
    CTXb[((size_t)(b*L_ + qi))*DM + h*HD + e] = f2b(o / Ltot);
  }
}

// ---------------- LayerNorm: wave-per-row, bf16x8 loads, zero LDS/barriers -----------
// grid: M/8 blocks x 512 threads (8 waves = 8 rows per block)
__global__ __launch_bounds__(512) void ln_kernel(const ushort* __restrict__ Xin,
    const ushort* __restrict__ AddB, const float* __restrict__ g, const float* __restrict__ beta,
    ushort* __restrict__ Xout)
{
  int wave = threadIdx.x >> 6, lane = threadIdx.x & 63;
  int row = blockIdx.x*8 + wave;
  size_t base = (size_t)row*DM + lane*8;
  bf16x8 xv = *(const bf16x8*)(Xin + base);
  float v[8];
  #pragma unroll
  for (int j = 0; j < 8; j++) v[j] = b2f((ushort)xv[j]);
  if (AddB) {
    bf16x8 av = *(const bf16x8*)(AddB + base);
    #pragma unroll
    for (int j = 0; j < 8; j++) v[j] += b2f((ushort)av[j]);
  }
  float s = 0.f;
  #pragma unroll
  for (int j = 0; j < 8; j++) s += v[j];
  #pragma unroll
  for (int off = 32; off; off >>= 1) s += __shfl_xor(s, off);
  float mean = s * (1.f/DM);
  float q = 0.f;
  #pragma unroll
  for (int j = 0; j < 8; j++) { float d = v[j] - mean; q += d*d; }
  #pragma unroll
  for (int off = 32; off; off >>= 1) q += __shfl_xor(q, off);
  float sq = sqrtf(q * (1.f/DM) + 1e-5f);
  float4 g0 = *(const float4*)(g + lane*8),  g1v = *(const float4*)(g + lane*8 + 4);
  float4 b0 = *(const float4*)(beta + lane*8), b1v = *(const float4*)(beta + lane*8 + 4);
  float gg[8] = {g0.x,g0.y,g0.z,g0.w,g1v.x,g1v.y,g1v.z,g1v.w};
  float bb[8] = {b0.x,b0.y,b0.z,b0.w,b1v.x,b1v.y,b1v.z,b1v.w};
  bf16x8 ov;
  #pragma unroll
  for (int j = 0; j < 8; j++) ov[j] = (short)f2b((v[j] - mean) / sq * gg[j] + bb[j]);
  *(bf16x8*)(Xout + base) = ov;
}

// ---------------- partial mean pool (256 blocks, coalesced) + classifier -------------
__global__ __launch_bounds__(512) void poolp_kernel(const ushort* __restrict__ Xt, float* __restrict__ pooledP)
{
  int p = blockIdx.x;                 // b*64 + seg (256 blocks)
  int t = threadIdx.x;
  int b = p >> 6, seg = p & 63;
  const ushort* base = Xt + ((size_t)(b*L_ + seg*16))*DM + t;
  float s = 0.f;
  #pragma unroll
  for (int l = 0; l < 16; l++) s += b2f(base[(size_t)l*DM]);
  pooledP[(size_t)p*DM + t] = s;
}

__global__ __launch_bounds__(64) void cls_kernel(const float* __restrict__ pooledP,
    const float* __restrict__ Wc, const float* __restrict__ bc, float* __restrict__ out)
{
  int o = blockIdx.x;
  int b = o/10, c = o%10, t = threadIdx.x;
  float s = 0.f;
  for (int d = t; d < DM; d += 64) {
    float pa = 0.f;
    #pragma unroll
    for (int s8 = 0; s8 < 64; s8 += 8) {
      float vv[8];
      #pragma unroll
      for (int j = 0; j < 8; j++) vv[j] = pooledP[(size_t)(b*64 + s8 + j)*DM + d];
      #pragma unroll
      for (int j = 0; j < 8; j++) pa += vv[j];
    }
    s += pa * (1.f/L_) * Wc[d*10 + c];
  }
  #pragma unroll
  for (int off = 32; off; off >>= 1) s += __shfl_xor(s, off);
  if (t == 0) out[o] = bc[c] + s;
}

extern "C" void kernel_launch(void* const* d_in, const int* in_sizes, int n_in,
                              void* d_out, int out_size, void* d_ws, size_t ws_size,
                              hipStream_t stream)
{
  const float* src   = (const float*)d_in[0];
  const int*   idxs  = (const int*)d_in[1];
  const float* Wemb  = (const float*)d_in[2];
  const float* bemb  = (const float*)d_in[3];
  const float* Wq    = (const float*)d_in[4];
  const float* bq    = (const float*)d_in[5];
  const float* Wk    = (const float*)d_in[6];
  const float* bk    = (const float*)d_in[7];
  const float* Wv    = (const float*)d_in[8];
  const float* bv    = (const float*)d_in[9];
  const float* Wo    = (const float*)d_in[10];
  const float* bo    = (const float*)d_in[11];
  const float* g1    = (const float*)d_in[12];
  const float* beta1 = (const float*)d_in[13];
  const float* W1    = (const float*)d_in[14];
  const float* bf1   = (const float*)d_in[15];
  const float* W2    = (const float*)d_in[16];
  const float* bf2   = (const float*)d_in[17];
  const float* g2    = (const float*)d_in[18];
  const float* beta2 = (const float*)d_in[19];
  const float* gf    = (const float*)d_in[20];
  const float* betaf = (const float*)d_in[21];
  const float* Wc    = (const float*)d_in[22];
  const float* bc    = (const float*)d_in[23];
  float* out = (float*)d_out;

  float* wsf = (float*)d_ws;
  // attention scratch in [0, 2097152); pooledP reuses it AFTER the layers (Pacc dead)
  float*  Pacc  = wsf;                              // 573,440 fl
  float*  VmeanP = wsf + 573440;                    // 32,768 fl (ends 606208 < 2097152)
  float*  pooledP = wsf + 606208;                   // 131,072 fl (ends 737280 < 2097152; used post-layers)
  ushort* Xt    = (ushort*)(wsf + 2097152);         // bf16 trunk: [2097152, 3145728)
  ushort* CTXb  = (ushort*)(wsf + 3145728);         // [3145728, 4194304)
  ushort* QKVb  = (ushort*)(wsf + 4194304);         // bf16 QKV: [4194304, 7340032) fl
  ushort* Ob    = (ushort*)(wsf + 7340032);         // bf16 Wo out: [7340032, 8388608) fl
  ushort* H     = (ushort*)(wsf + 4194304);         // FFN hidden bf16 (QKVb+Ob dead by FFN1)
  ushort* Yb    = (ushort*)(wsf + 8388608);         // bf16 FFN2 out: [8388608, 9437184) fl
  ushort* Wqkvt = (ushort*)(wsf + 10485760);        // 786,432 fl
  ushort* Wot   = (ushort*)(wsf + 11272192);        // 262,144 fl
  ushort* W1t   = (ushort*)(wsf + 11534336);        // 1,048,576 fl
  ushort* W2t   = (ushort*)(wsf + 12582912);        // 1,048,576 fl
  float*  bqkv  = wsf + 13631488;                   // 3,072
  float*  Msc   = wsf + 13634560;                   // 32,768 (dead after topk)
  float*  Pm    = wsf + 13634560;                   // alias Msc: 8,960
  float*  Pl    = wsf + 13634560 + 8960;            // alias Msc: 8,960
  float*  Vmean = wsf + 13667328;                   // 2,048
  int*    idx_top = (int*)(wsf + 13685760);         // 1,120

  // weight conversion: QKV merged (z = which*2+layer), others layer-batched
  wconv_qkv_kernel<<<dim3(DM/32, DM/32, 6), 256, 0, stream>>>(Wq, Wk, Wv, Wqkvt);
  wconv_kernel<<<dim3(DM/32, DM/32, 2), 256, 0, stream>>>(Wo, Wot, DM, DM, (size_t)DM*DM, (size_t)DM*DM);
  wconv_kernel<<<dim3(DFF/32, DM/32, 2), 256, 0, stream>>>(W1, W1t, DM, DFF, (size_t)DM*DFF, (size_t)DFF*DM);
  wconv_kernel<<<dim3(DM/32, DFF/32, 2), 256, 0, stream>>>(W2, W2t, DFF, DM, (size_t)DFF*DM, (size_t)DM*DFF);
  bcat_kernel<<<12, 256, 0, stream>>>(bq, bk, bv, bqkv);

  const int M = B_ * L_; // 4096
  embed_kernel<<<M, 512, 0, stream>>>(src, Wemb, bemb, Xt);

  for (int l = 0; l < 2; l++) {
    const size_t vo = (size_t)l*DM;
    // QKV: [4096,512] x [512,1536] -> bf16 out, 12x32 = 384 blocks (128x128 tiles)
    mfma_gemm<128,128,3><<<dim3(QS/128, M/128), 256, 0, stream>>>(
        Xt, Wqkvt + (size_t)l*QS*DM, bqkv + (size_t)l*QS, nullptr, nullptr, QKVb, M, QS, DM);
    qksample_kernel<<<B_*NH*L_, 64, 0, stream>>>(QKVb, idxs + (size_t)l*L_*KS, Msc);
    topk_kernel<<<B_*NH, 64, 0, stream>>>(Msc, idx_top);
    vmean_part_kernel<<<B_*NH*VSEG, 64, 0, stream>>>(QKVb, VmeanP);
    vmean_merge_kernel<<<B_*NH, 64, 0, stream>>>(VmeanP, Vmean);
    ctxfill_kernel<<<M, 512, 0, stream>>>(Vmean, CTXb);
    attn_part_kernel<<<B_*NH*NCH*4, 256, 0, stream>>>(QKVb, idx_top, Pacc, Pm, Pl);
    attn_merge_kernel<<<B_*NH, 256, 0, stream>>>(Pacc, Pm, Pl, idx_top, CTXb);
    // Wo: [4096,512] x [512,512] -> bf16 delta Ob (residual added in ln1)
    mfma_gemm<64,64,3><<<dim3(DM/64, M/64), 256, 0, stream>>>(
        CTXb, Wot + (size_t)l*DM*DM, bo + vo, nullptr, nullptr, Ob, M, DM, DM);
    ln_kernel<<<M/8, 512, 0, stream>>>(Xt, Ob, g1 + vo, beta1 + vo, Xt);
    // FFN1: [4096,512] x [512,2048] -> gelu bf16, 16x32 = 512 blocks (128x128 tiles)
    mfma_gemm<128,128,1><<<dim3(DFF/128, M/128), 256, 0, stream>>>(
        Xt, W1t + (size_t)l*DFF*DM, bf1 + (size_t)l*DFF, nullptr, nullptr, H, M, DFF, DM);
    // FFN2: [4096,2048] x [2048,512] -> bf16 delta Yb (residual added in ln2)
    mfma_gemm<64,64,3><<<dim3(DM/64, M/64), 256, 0, stream>>>(
        H, W2t + (size_t)l*DM*DFF, bf2 + vo, nullptr, nullptr, Yb, M, DM, DFF);
    ln_kernel<<<M/8, 512, 0, stream>>>(Xt, Yb, g2 + vo, beta2 + vo, Xt);
  }
  ln_kernel<<<M/8, 512, 0, stream>>>(Xt, nullptr, gf, betaf, Xt);
  poolp_kernel<<<B_*64, 512, 0, stream>>>(Xt, pooledP);
  cls_kernel<<<40, 64, 0, stream>>>(pooledP, Wc, bc, out);
}

// Round 24
// 349.622 us; speedup vs baseline: 1.2782x; 1.0510x over previous
//
#include <hip/hip_runtime.h>
#include <hip/hip_bf16.h>
#include <math.h>

#define B_ 4
#define L_ 1024
#define DM 512
#define NH 8
#define HD 64
#define DFF 2048
#define KS 35
#define QS 1536   // packed QKV row stride
#define CH 128    // attention key chunk
#define NCH (L_/CH)
#define VSEG 16   // V-mean segments per head

typedef __attribute__((ext_vector_type(8))) short bf16x8;
typedef __attribute__((ext_vector_type(4))) float f32x4;

__device__ inline ushort f2b(float f){
  __hip_bfloat16 h = __float2bfloat16(f);
  return *reinterpret_cast<ushort*>(&h);
}
__device__ inline float b2f(ushort u){
  union { unsigned int i; float f; } x; x.i = ((unsigned int)u) << 16; return x.f;
}
__device__ inline float gelu_exact(float x){
  return 0.5f*x*(1.0f+erff(x*0.7071067811865476f));
}

#define GLOAD16(g, l) __builtin_amdgcn_global_load_lds( \
    (const __attribute__((address_space(1))) void*)(g), \
    (__attribute__((address_space(3))) void*)(l), 16, 0, 0)

// ---------------- weight convert + transpose to bf16 [N][K] (layer-batched) ----------
__global__ __launch_bounds__(256) void wconv_kernel(const float* __restrict__ W,
    ushort* __restrict__ Wt, int K, int N, size_t sStride, size_t dStride)
{
  W  += (size_t)blockIdx.z * sStride;
  Wt += (size_t)blockIdx.z * dStride;
  __shared__ float tile[32][33];
  int n0 = blockIdx.x*32, k0 = blockIdx.y*32;
  int tx = threadIdx.x & 31, ty = threadIdx.x >> 5;
  #pragma unroll
  for (int i = ty; i < 32; i += 8) tile[i][tx] = W[(size_t)(k0+i)*N + n0+tx];
  __syncthreads();
  #pragma unroll
  for (int i = ty; i < 32; i += 8) Wt[(size_t)(n0+i)*K + k0+tx] = f2b(tile[tx][i]);
}

// QKV variant: z in [0,6) = which*2 + layer; one dispatch for all six 512x512 blocks
__global__ __launch_bounds__(256) void wconv_qkv_kernel(const float* __restrict__ Wq,
    const float* __restrict__ Wk, const float* __restrict__ Wv, ushort* __restrict__ Wt)
{
  int z = blockIdx.z, which = z >> 1, l = z & 1;
  const float* W = ((which == 0) ? Wq : (which == 1) ? Wk : Wv) + (size_t)l*DM*DM;
  ushort* dst = Wt + (size_t)l*QS*DM + (size_t)which*512*DM;
  __shared__ float tile[32][33];
  int n0 = blockIdx.x*32, k0 = blockIdx.y*32;
  int tx = threadIdx.x & 31, ty = threadIdx.x >> 5;
  #pragma unroll
  for (int i = ty; i < 32; i += 8) tile[i][tx] = W[(size_t)(k0+i)*DM + n0+tx];
  __syncthreads();
  #pragma unroll
  for (int i = ty; i < 32; i += 8) dst[(size_t)(n0+i)*DM + k0+tx] = f2b(tile[tx][i]);
}

__global__ __launch_bounds__(256) void bcat_kernel(const float* __restrict__ bq,
    const float* __restrict__ bk, const float* __restrict__ bv, float* __restrict__ bqkv)
{
  int i = blockIdx.x*256 + threadIdx.x;   // 0..3071
  if (i >= 2*QS) return;
  int l = i / QS, j = i - l*QS;
  const float* src = (j < 512) ? bq : (j < 1024 ? bk : bv);
  bqkv[i] = src[l*DM + (j & 511)];
}

// ---------------- bf16 MFMA GEMM: dbuf, K=64/tile, COUNTED vmcnt (T4), XCD-swizzled --
// MODE 0: f32 out, 1: gelu->bf16 out, 2: +R f32 out, 3: plain bf16 out
template<int BM, int BN, int MODE>
__global__ __launch_bounds__(256) void mfma_gemm(
    const ushort* __restrict__ A, const ushort* __restrict__ Bt,
    const float* __restrict__ bias, const float* __restrict__ R,
    float* __restrict__ Cf, ushort* __restrict__ Cb,
    int M, int N, int K)
{
  constexpr int MF = BM/32;          // A fragments per wave
  constexpr int NF = BN/32;          // B fragments per wave
  constexpr int AIT = BM*4/256;      // staging iters per K=32 sub-tile
  constexpr int BIT = BN*4/256;
  constexpr int LT = (AIT + BIT)*2;  // gload_lds ops per K=64 tile per thread (4/6/8)
  __shared__ __align__(16) ushort As[2][2][BM*32];
  __shared__ __align__(16) ushort Bs[2][2][BN*32];
  const int t = threadIdx.x, lane = t & 63, w = t >> 6, wr = w >> 1, wc = w & 1;

  // XCD-chunked bijective swizzle (all grids are multiples of 8)
  const int gx = gridDim.x;
  const int nwg = gx * gridDim.y;
  const int bid = blockIdx.y*gx + blockIdx.x;
  const int swz = (bid & 7)*(nwg >> 3) + (bid >> 3);
  const int row0 = (swz / gx)*BM, col0 = (swz % gx)*BN;

  // staging: linear LDS dest, inverse-swizzled global source (per K=32 sub-tile)
  const ushort* aSrc[AIT]; int aDst[AIT];
  #pragma unroll
  for (int j = 0; j < AIT; j++) {
    int ch = j*256 + t, r = ch >> 2, cc = ch & 3, cs = cc ^ ((r >> 1) & 3);
    aSrc[j] = A + (size_t)(row0 + r)*K + cs*8;
    aDst[j] = ch*16;
  }
  const ushort* bSrc[BIT]; int bDst[BIT];
  #pragma unroll
  for (int j = 0; j < BIT; j++) {
    int ch = j*256 + t, r = ch >> 2, cc = ch & 3, cs = cc ^ ((r >> 1) & 3);
    bSrc[j] = Bt + (size_t)(col0 + r)*K + cs*8;
    bDst[j] = ch*16;
  }
  // fragment read offsets (swizzled, within one sub-tile)
  int aOff[MF], bOff[NF];
  #pragma unroll
  for (int m = 0; m < MF; m++) {
    int r = wr*(BM/2) + m*16 + (lane & 15);
    aOff[m] = r*64 + (((lane >> 4)*16) ^ (((r >> 1) & 3) << 4));
  }
  #pragma unroll
  for (int n = 0; n < NF; n++) {
    int r = wc*(BN/2) + n*16 + (lane & 15);
    bOff[n] = r*64 + (((lane >> 4)*16) ^ (((r >> 1) & 3) << 4));
  }
  f32x4 zero = {0.f, 0.f, 0.f, 0.f};
  f32x4 acc[MF][NF];
  #pragma unroll
  for (int m = 0; m < MF; m++)
    #pragma unroll
    for (int n = 0; n < NF; n++) acc[m][n] = zero;

#define STAGE_TILE(kt, buf) do { \
    _Pragma("unroll") \
    for (int j = 0; j < AIT; j++) GLOAD16(aSrc[j] + (kt),      (char*)As[buf][0] + aDst[j]); \
    _Pragma("unroll") \
    for (int j = 0; j < AIT; j++) GLOAD16(aSrc[j] + (kt) + 32, (char*)As[buf][1] + aDst[j]); \
    _Pragma("unroll") \
    for (int j = 0; j < BIT; j++) GLOAD16(bSrc[j] + (kt),      (char*)Bs[buf][0] + bDst[j]); \
    _Pragma("unroll") \
    for (int j = 0; j < BIT; j++) GLOAD16(bSrc[j] + (kt) + 32, (char*)Bs[buf][1] + bDst[j]); \
  } while (0)

  const int nk = K >> 6;             // K/64, always >= 8 here
  // prologue: 2-deep prefetch — T0 -> buf0, T1 -> buf1
  STAGE_TILE(0, 0);
  STAGE_TILE(64, 1);

  for (int ki = 0; ki < nk; ki++) {
    const int cur = ki & 1;
    // wait for tile ki's loads; tile ki+1's LT loads may remain in flight (never 0 mid-loop)
    if (ki + 1 < nk) {
      if constexpr (LT == 8)      asm volatile("s_waitcnt vmcnt(8)" ::: "memory");
      else if constexpr (LT == 6) asm volatile("s_waitcnt vmcnt(6)" ::: "memory");
      else                        asm volatile("s_waitcnt vmcnt(4)" ::: "memory");
    } else {
      asm volatile("s_waitcnt vmcnt(0)" ::: "memory");
    }
    __builtin_amdgcn_sched_barrier(0);
    __builtin_amdgcn_s_barrier();      // all waves have tile ki resident
    #pragma unroll
    for (int s = 0; s < 2; s++) {      // two K=32 sub-steps, same accumulation order
      bf16x8 af[MF], bfr[NF];
      #pragma unroll
      for (int m = 0; m < MF; m++) af[m] = *(const bf16x8*)((const char*)As[cur][s] + aOff[m]);
      #pragma unroll
      for (int n = 0; n < NF; n++) bfr[n] = *(const bf16x8*)((const char*)Bs[cur][s] + bOff[n]);
      #pragma unroll
      for (int m = 0; m < MF; m++)
        #pragma unroll
        for (int n = 0; n < NF; n++)
          acc[m][n] = __builtin_amdgcn_mfma_f32_16x16x32_bf16(af[m], bfr[n], acc[m][n], 0, 0, 0);
    }
    __builtin_amdgcn_s_barrier();      // all waves done reading buf[cur]
    if (ki + 2 < nk) STAGE_TILE((ki + 2) << 6, cur);   // refill the just-read buffer
  }
#undef STAGE_TILE

  #pragma unroll
  for (int m = 0; m < MF; m++) {
    int rb = row0 + wr*(BM/2) + m*16 + ((lane >> 4) << 2);
    #pragma unroll
    for (int n = 0; n < NF; n++) {
      int c = col0 + wc*(BN/2) + n*16 + (lane & 15);
      float bv = bias[c];
      #pragma unroll
      for (int j = 0; j < 4; j++) {
        size_t idx = (size_t)(rb + j)*N + c;
        float v = acc[m][n][j] + bv;
        if (MODE == 1)      Cb[idx] = f2b(gelu_exact(v));
        else if (MODE == 2) Cf[idx] = v + R[idx];
        else if (MODE == 3) Cb[idx] = f2b(v);
        else                Cf[idx] = v;
      }
    }
  }
}

// ---------------- embed + positional encoding (bf16 trunk out) ----------------
__global__ __launch_bounds__(512) void embed_kernel(const float* __restrict__ src,
    const float* __restrict__ Wemb, const float* __restrict__ bemb,
    ushort* __restrict__ Xt)
{
  int row = blockIdx.x, l = row & (L_-1), t = threadIdx.x;
  __shared__ float s_src[32];
  if (t < 32) s_src[t] = src[row*32 + t];
  __syncthreads();
  float acc = bemb[t];
  #pragma unroll
  for (int k = 0; k < 32; k++) acc += s_src[k]*Wemb[k*DM + t];
  int i2 = t & ~1;
  float freq = expf((float)i2 * (-9.210340371976184f/512.0f));
  float ang = (float)l * freq;
  acc += (t & 1) ? cosf(ang) : sinf(ang);
  Xt[(size_t)row*DM + t] = f2b(acc);
}

// ---------------- FUSED: vmean_part (bid<512) + qksample (bid>=512), 64 thr ----------
__global__ __launch_bounds__(64) void qkvm_kernel(const ushort* __restrict__ QKVb,
    const int* __restrict__ idx_s, float* __restrict__ Msc, float* __restrict__ VmeanP)
{
  int bid = blockIdx.x;
  if (bid < 512) {
    // ---- vmean_part body ----
    int gid = bid;
    int seg = gid & (VSEG-1), bh = gid >> 4;
    int h = bh & 7, b = bh >> 3;
    int e = threadIdx.x;
    const ushort* Vb = QKVb + 1024 + h*HD + ((size_t)(b*L_ + seg*(L_/VSEG)))*QS;
    float s = 0.f;
    for (int l0 = 0; l0 < L_/VSEG; l0 += 8) {
      float vv[8];
      #pragma unroll
      for (int j = 0; j < 8; j++) vv[j] = b2f(Vb[(size_t)(l0+j)*QS + e]);
      #pragma unroll
      for (int j = 0; j < 8; j++) s += vv[j];
    }
    VmeanP[gid*HD + e] = s;
    return;
  }
  // ---- qksample body ----
  int gid = bid - 512;               // (b*8+h)*1024 + i
  int i = gid & (L_-1), h = (gid >> 10) & 7, b = gid >> 13;
  int t = threadIdx.x;
  int j4 = t >> 2, e4 = t & 3;       // lane = j4*4 + e4
  const ushort* Qrow = QKVb + ((size_t)(b*L_ + i))*QS + h*HD + e4*16;
  bf16x8 qa = *(const bf16x8*)(Qrow);
  bf16x8 qb = *(const bf16x8*)(Qrow + 8);
  float q[16];
  #pragma unroll
  for (int x = 0; x < 8; x++) { q[x] = b2f((ushort)qa[x]); q[8+x] = b2f((ushort)qb[x]); }
  const ushort* Kbase = QKVb + 512 + h*HD + (size_t)b*L_*QS + e4*16;
  const int* idq = idx_s + i*KS;
  float mx = -3.4e38f, sm = 0.f;
  #pragma unroll
  for (int p = 0; p < 3; p++) {
    int j = p*16 + j4;
    int jc = (j < KS) ? j : 0;       // inactive lanes redo j=0 (result discarded)
    int s = idq[jc];
    const ushort* Kr = Kbase + (size_t)s*QS;
    bf16x8 ka = *(const bf16x8*)(Kr);
    bf16x8 kb = *(const bf16x8*)(Kr + 8);
    float d = 0.f;
    #pragma unroll
    for (int x = 0; x < 8; x++) d += q[x]   * b2f((ushort)ka[x]);
    #pragma unroll
    for (int x = 0; x < 8; x++) d += q[8+x] * b2f((ushort)kb[x]);
    d += __shfl_xor(d, 1);
    d += __shfl_xor(d, 2);
    if (j < KS && e4 == 0) { mx = fmaxf(mx, d); sm += d; }
  }
  #pragma unroll
  for (int off = 4; off < 64; off <<= 1) {
    mx = fmaxf(mx, __shfl_xor(mx, off));
    sm += __shfl_xor(sm, off);
  }
  if (t == 0) Msc[gid] = mx - sm*(1.0f/KS);
}

// ---------------- FUSED: topk (bid<32) + vmean_merge (bid>=32), 64 thr ---------------
__global__ __launch_bounds__(64) void topk_vm_kernel(const float* __restrict__ Msc,
    int* __restrict__ idx_top, const float* __restrict__ VmeanP, float* __restrict__ Vmean)
{
  int bid = blockIdx.x, t = threadIdx.x;
  if (bid >= 32) {
    // ---- vmean_merge body ----
    int bh = bid - 32, e = t;
    float s = 0.f;
    #pragma unroll
    for (int seg = 0; seg < VSEG; seg++) s += VmeanP[(bh*VSEG + seg)*HD + e];
    Vmean[bh*HD + e] = s * (1.f/L_);
    return;
  }
  // ---- topk body (register-resident, no LDS) ----
  int bh = bid;
  float v[16];
  #pragma unroll
  for (int r = 0; r < 16; r++) v[r] = Msc[(size_t)bh*L_ + r*64 + t];
  for (int sel = 0; sel < KS; sel++) {
    float bv = -3.4e38f; int br = 0;
    #pragma unroll
    for (int r = 0; r < 16; r++) {
      bool gt = v[r] > bv;
      bv = gt ? v[r] : bv;
      br = gt ? r : br;
    }
    int bi = br*64 + t;
    #pragma unroll
    for (int off = 32; off; off >>= 1) {
      float ov = __shfl_xor(bv, off); int oi = __shfl_xor(bi, off);
      if (ov > bv || (ov == bv && oi < bi)) { bv = ov; bi = oi; }
    }
    if (t == 0) idx_top[bh*KS + sel] = bi;
    if ((bi & 63) == t) v[bi >> 6] = -3.4e38f;
  }
}

// ---------------- FUSED: attn_part (bid<1024) + ctxfill (bid>=1024), 256 thr ---------
// ctx blocks: row pair = (bid-1024)*2, each thread writes 4 elems (2 rows x 2 halves)
__global__ __launch_bounds__(256) void attnpart_ctx_kernel(const ushort* __restrict__ QKVb,
    const int* __restrict__ idx_top, const float* __restrict__ Vmean, ushort* __restrict__ CTXb,
    float* __restrict__ Pacc, float* __restrict__ Pm, float* __restrict__ Pl)
{
  int bid = blockIdx.x;
  int t = threadIdx.x;
  __shared__ float qs[9][68];          // scaled Q rows (padded pitch)
  __shared__ float sc[9][132];         // scores -> exp'd scores
  __shared__ float sm[9], sl[9];
  if (bid >= 1024) {
    // ---- ctxfill body: 2 rows per block ----
    int r0 = (bid - 1024)*2;
    int b = r0 >> 10;
    ushort v0 = f2b(Vmean[b*DM + t]);
    ushort v1 = f2b(Vmean[b*DM + 256 + t]);
    CTXb[(size_t)r0*DM + t] = v0;
    CTXb[(size_t)r0*DM + 256 + t] = v1;
    int r1 = r0 + 1;
    CTXb[(size_t)r1*DM + t] = v0;
    CTXb[(size_t)r1*DM + 256 + t] = v1;
    return;
  }
  // ---- attn_part body ----
  int gid = bid;
  int q = gid & 3, c = (gid >> 2) & 7, bh = gid >> 5;
  int h = bh & 7, b = bh >> 3;
  int chunk = bh*NCH + c;
  int u0 = q*9;
  int NU = (q == 3) ? 8 : 9;

  // load + scale this block's Q rows
  for (int idx = t; idx < NU*64; idx += 256) {
    int ul = idx >> 6, e = idx & 63;
    int qi = idx_top[bh*KS + u0 + ul];
    qs[ul][e] = b2f(QKVb[((size_t)(b*L_ + qi))*QS + h*HD + e]) * 0.125f;
  }
  __syncthreads();

  // scores: thread k = t&127 owns one key; K row in 8 bf16x8 regs (convert inline)
  {
    int k = t & 127, par = t >> 7;
    const ushort* Kr = QKVb + ((size_t)(b*L_ + c*CH + k))*QS + 512 + h*HD;
    bf16x8 kreg[8];
    #pragma unroll
    for (int i8 = 0; i8 < 8; i8++) kreg[i8] = *(const bf16x8*)(Kr + i8*8);
    for (int ul = par; ul < NU; ul += 2) {
      float d = 0.f;
      #pragma unroll
      for (int i8 = 0; i8 < 8; i8++) {
        bf16x8 kv = kreg[i8];
        float4 qa = *(const float4*)&qs[ul][i8*8];
        float4 qb = *(const float4*)&qs[ul][i8*8 + 4];
        d += qa.x*b2f((ushort)kv[0]) + qa.y*b2f((ushort)kv[1])
           + qa.z*b2f((ushort)kv[2]) + qa.w*b2f((ushort)kv[3]);
        d += qb.x*b2f((ushort)kv[4]) + qb.y*b2f((ushort)kv[5])
           + qb.z*b2f((ushort)kv[6]) + qb.w*b2f((ushort)kv[7]);
      }
      sc[ul][k] = d;
    }
  }
  __syncthreads();

  // softmax per ul: 4 threads/row
  {
    int ul = t >> 2, sub = t & 3;
    if (ul < NU) {
      float m = -3.4e38f;
      for (int i = sub; i < 128; i += 4) m = fmaxf(m, sc[ul][i]);
      m = fmaxf(m, __shfl_xor(m, 1));
      m = fmaxf(m, __shfl_xor(m, 2));
      float l = 0.f;
      for (int i = sub; i < 128; i += 4) {
        float ev = expf(sc[ul][i] - m);
        sc[ul][i] = ev;
        l += ev;
      }
      l += __shfl_xor(l, 1);
      l += __shfl_xor(l, 2);
      if (sub == 0) { sm[ul] = m; sl[ul] = l; }
    }
  }
  __syncthreads();

  // partial PV: thread = (ug, e); 8-deep manual load pipeline (ILP)
  {
    int e = t & 63, ug = t >> 6;
    const ushort* Vb = QKVb + 1024 + h*HD + ((size_t)(b*L_ + c*CH))*QS;
    float acc[3] = {0.f, 0.f, 0.f};
    for (int kb0 = 0; kb0 < CH; kb0 += 8) {
      float vv[8];
      #pragma unroll
      for (int j = 0; j < 8; j++) vv[j] = b2f(Vb[(size_t)(kb0 + j)*QS + e]);   // 8 loads in flight
      #pragma unroll
      for (int j = 0; j < 8; j++) {
        #pragma unroll
        for (int iu = 0; iu < 3; iu++) {
          int ul = ug + iu*4;
          if (ul < NU) acc[iu] += sc[ul][kb0 + j] * vv[j];   // sc read is wave-uniform broadcast
        }
      }
    }
    #pragma unroll
    for (int iu = 0; iu < 3; iu++) {
      int ul = ug + iu*4;
      if (ul < NU) Pacc[((size_t)chunk*35 + u0 + ul)*64 + e] = acc[iu];
    }
  }
  if (t < NU) { Pm[chunk*35 + u0 + t] = sm[t]; Pl[chunk*35 + u0 + t] = sl[t]; }
}

// ---------------- phase B: merge partials, scatter bf16 ctx ----------------
__global__ __launch_bounds__(256) void attn_merge_kernel(const float* __restrict__ Pacc,
    const float* __restrict__ Pm, const float* __restrict__ Pl,
    const int* __restrict__ idx_top, ushort* __restrict__ CTXb)
{
  int bh = blockIdx.x;
  int h = bh & 7, b = bh >> 3;
  int t = threadIdx.x;
  __shared__ float m8[NCH*35], l8[NCH*35];
  for (int i = t; i < NCH*35; i += 256) {
    int c = i / 35, u = i - c*35;
    m8[c*35 + u] = Pm[((size_t)bh*NCH + c)*35 + u];
    l8[c*35 + u] = Pl[((size_t)bh*NCH + c)*35 + u];
  }
  __syncthreads();
  int e = t & 63, ug = t >> 6;
  #pragma unroll
  for (int iu = 0; iu < 9; iu++) {
    int u = ug + iu*4;
    if (u >= 35) break;
    float M = -3.4e38f;
    #pragma unroll
    for (int c = 0; c < NCH; c++) M = fmaxf(M, m8[c*35 + u]);
    float Ltot = 0.f, o = 0.f;
    #pragma unroll
    for (int c = 0; c < NCH; c++) {
      float w = expf(m8[c*35 + u] - M);
      Ltot += w * l8[c*35 + u];
      o += w * Pacc[(((size_t)bh*NCH + c)*35 + u)*64 + e];
    }
    int qi = idx_top[bh*KS + u];
    CTXb[((size_t)(b*L_ + qi))*DM + h*HD + e] = f2b(o / Ltot);
  }
}

// ---------------- LayerNorm: wave-per-row, bf16x8 loads, zero LDS/barriers -----------
// grid: M/8 blocks x 512 threads (8 waves = 8 rows per block)
__global__ __launch_bounds__(512) void ln_kernel(const ushort* __restrict__ Xin,
    const ushort* __restrict__ AddB, const float* __restrict__ g, const float* __restrict__ beta,
    ushort* __restrict__ Xout)
{
  int wave = threadIdx.x >> 6, lane = threadIdx.x & 63;
  int row = blockIdx.x*8 + wave;
  size_t base = (size_t)row*DM + lane*8;
  bf16x8 xv = *(const bf16x8*)(Xin + base);
  float v[8];
  #pragma unroll
  for (int j = 0; j < 8; j++) v[j] = b2f((ushort)xv[j]);
  if (AddB) {
    bf16x8 av = *(const bf16x8*)(AddB + base);
    #pragma unroll
    for (int j = 0; j < 8; j++) v[j] += b2f((ushort)av[j]);
  }
  float s = 0.f;
  #pragma unroll
  for (int j = 0; j < 8; j++) s += v[j];
  #pragma unroll
  for (int off = 32; off; off >>= 1) s += __shfl_xor(s, off);
  float mean = s * (1.f/DM);
  float q = 0.f;
  #pragma unroll
  for (int j = 0; j < 8; j++) { float d = v[j] - mean; q += d*d; }
  #pragma unroll
  for (int off = 32; off; off >>= 1) q += __shfl_xor(q, off);
  float sq = sqrtf(q * (1.f/DM) + 1e-5f);
  float4 g0 = *(const float4*)(g + lane*8),  g1v = *(const float4*)(g + lane*8 + 4);
  float4 b0 = *(const float4*)(beta + lane*8), b1v = *(const float4*)(beta + lane*8 + 4);
  float gg[8] = {g0.x,g0.y,g0.z,g0.w,g1v.x,g1v.y,g1v.z,g1v.w};
  float bb[8] = {b0.x,b0.y,b0.z,b0.w,b1v.x,b1v.y,b1v.z,b1v.w};
  bf16x8 ov;
  #pragma unroll
  for (int j = 0; j < 8; j++) ov[j] = (short)f2b((v[j] - mean) / sq * gg[j] + bb[j]);
  *(bf16x8*)(Xout + base) = ov;
}

// ---------------- partial mean pool (256 blocks, coalesced) + classifier -------------
__global__ __launch_bounds__(512) void poolp_kernel(const ushort* __restrict__ Xt, float* __restrict__ pooledP)
{
  int p = blockIdx.x;                 // b*64 + seg (256 blocks)
  int t = threadIdx.x;
  int b = p >> 6, seg = p & 63;
  const ushort* base = Xt + ((size_t)(b*L_ + seg*16))*DM + t;
  float s = 0.f;
  #pragma unroll
  for (int l = 0; l < 16; l++) s += b2f(base[(size_t)l*DM]);
  pooledP[(size_t)p*DM + t] = s;
}

__global__ __launch_bounds__(64) void cls_kernel(const float* __restrict__ pooledP,
    const float* __restrict__ Wc, const float* __restrict__ bc, float* __restrict__ out)
{
  int o = blockIdx.x;
  int b = o/10, c = o%10, t = threadIdx.x;
  float s = 0.f;
  for (int d = t; d < DM; d += 64) {
    float pa = 0.f;
    #pragma unroll
    for (int s8 = 0; s8 < 64; s8 += 8) {
      float vv[8];
      #pragma unroll
      for (int j = 0; j < 8; j++) vv[j] = pooledP[(size_t)(b*64 + s8 + j)*DM + d];
      #pragma unroll
      for (int j = 0; j < 8; j++) pa += vv[j];
    }
    s += pa * (1.f/L_) * Wc[d*10 + c];
  }
  #pragma unroll
  for (int off = 32; off; off >>= 1) s += __shfl_xor(s, off);
  if (t == 0) out[o] = bc[c] + s;
}

extern "C" void kernel_launch(void* const* d_in, const int* in_sizes, int n_in,
                              void* d_out, int out_size, void* d_ws, size_t ws_size,
                              hipStream_t stream)
{
  const float* src   = (const float*)d_in[0];
  const int*   idxs  = (const int*)d_in[1];
  const float* Wemb  = (const float*)d_in[2];
  const float* bemb  = (const float*)d_in[3];
  const float* Wq    = (const float*)d_in[4];
  const float* bq    = (const float*)d_in[5];
  const float* Wk    = (const float*)d_in[6];
  const float* bk    = (const float*)d_in[7];
  const float* Wv    = (const float*)d_in[8];
  const float* bv    = (const float*)d_in[9];
  const float* Wo    = (const float*)d_in[10];
  const float* bo    = (const float*)d_in[11];
  const float* g1    = (const float*)d_in[12];
  const float* beta1 = (const float*)d_in[13];
  const float* W1    = (const float*)d_in[14];
  const float* bf1   = (const float*)d_in[15];
  const float* W2    = (const float*)d_in[16];
  const float* bf2   = (const float*)d_in[17];
  const float* g2    = (const float*)d_in[18];
  const float* beta2 = (const float*)d_in[19];
  const float* gf    = (const float*)d_in[20];
  const float* betaf = (const float*)d_in[21];
  const float* Wc    = (const float*)d_in[22];
  const float* bc    = (const float*)d_in[23];
  float* out = (float*)d_out;

  float* wsf = (float*)d_ws;
  // attention scratch in [0, 2097152); pooledP reuses it AFTER the layers (Pacc dead)
  float*  Pacc  = wsf;                              // 573,440 fl
  float*  VmeanP = wsf + 573440;                    // 32,768 fl (ends 606208 < 2097152)
  float*  pooledP = wsf + 606208;                   // 131,072 fl (ends 737280; used post-layers)
  ushort* Xt    = (ushort*)(wsf + 2097152);         // bf16 trunk: [2097152, 3145728)
  ushort* CTXb  = (ushort*)(wsf + 3145728);         // [3145728, 4194304)
  ushort* QKVb  = (ushort*)(wsf + 4194304);         // bf16 QKV: [4194304, 7340032) fl
  ushort* Ob    = (ushort*)(wsf + 7340032);         // bf16 Wo out: [7340032, 8388608) fl
  ushort* H     = (ushort*)(wsf + 4194304);         // FFN hidden bf16 (QKVb+Ob dead by FFN1)
  ushort* Yb    = (ushort*)(wsf + 8388608);         // bf16 FFN2 out: [8388608, 9437184) fl
  ushort* Wqkvt = (ushort*)(wsf + 10485760);        // 786,432 fl
  ushort* Wot   = (ushort*)(wsf + 11272192);        // 262,144 fl
  ushort* W1t   = (ushort*)(wsf + 11534336);        // 1,048,576 fl
  ushort* W2t   = (ushort*)(wsf + 12582912);        // 1,048,576 fl
  float*  bqkv  = wsf + 13631488;                   // 3,072
  float*  Msc   = wsf + 13634560;                   // 32,768 (dead after topk)
  float*  Pm    = wsf + 13634560;                   // alias Msc: 8,960
  float*  Pl    = wsf + 13634560 + 8960;            // alias Msc: 8,960
  float*  Vmean = wsf + 13667328;                   // 2,048
  int*    idx_top = (int*)(wsf + 13685760);         // 1,120

  // weight conversion: QKV merged (z = which*2+layer), others layer-batched
  wconv_qkv_kernel<<<dim3(DM/32, DM/32, 6), 256, 0, stream>>>(Wq, Wk, Wv, Wqkvt);
  wconv_kernel<<<dim3(DM/32, DM/32, 2), 256, 0, stream>>>(Wo, Wot, DM, DM, (size_t)DM*DM, (size_t)DM*DM);
  wconv_kernel<<<dim3(DFF/32, DM/32, 2), 256, 0, stream>>>(W1, W1t, DM, DFF, (size_t)DM*DFF, (size_t)DFF*DM);
  wconv_kernel<<<dim3(DM/32, DFF/32, 2), 256, 0, stream>>>(W2, W2t, DFF, DM, (size_t)DFF*DM, (size_t)DM*DFF);
  bcat_kernel<<<12, 256, 0, stream>>>(bq, bk, bv, bqkv);

  const int M = B_ * L_; // 4096
  embed_kernel<<<M, 512, 0, stream>>>(src, Wemb, bemb, Xt);

  for (int l = 0; l < 2; l++) {
    const size_t vo = (size_t)l*DM;
    // QKV: [4096,512] x [512,1536] -> bf16 out, 12x32 = 384 blocks (128x128 tiles)
    mfma_gemm<128,128,3><<<dim3(QS/128, M/128), 256, 0, stream>>>(
        Xt, Wqkvt + (size_t)l*QS*DM, bqkv + (size_t)l*QS, nullptr, nullptr, QKVb, M, QS, DM);
    // fused: vmean_part (512) + qksample (32768)
    qkvm_kernel<<<512 + B_*NH*L_, 64, 0, stream>>>(QKVb, idxs + (size_t)l*L_*KS, Msc, VmeanP);
    // fused: topk (32) + vmean_merge (32)
    topk_vm_kernel<<<64, 64, 0, stream>>>(Msc, idx_top, VmeanP, Vmean);
    // fused: attn_part (1024) + ctxfill (2048, 2 rows/block)
    attnpart_ctx_kernel<<<1024 + M/2, 256, 0, stream>>>(QKVb, idx_top, Vmean, CTXb, Pacc, Pm, Pl);
    attn_merge_kernel<<<B_*NH, 256, 0, stream>>>(Pacc, Pm, Pl, idx_top, CTXb);
    // Wo: [4096,512] x [512,512] -> bf16 delta Ob (residual added in ln1)
    mfma_gemm<64,64,3><<<dim3(DM/64, M/64), 256, 0, stream>>>(
        CTXb, Wot + (size_t)l*DM*DM, bo + vo, nullptr, nullptr, Ob, M, DM, DM);
    ln_kernel<<<M/8, 512, 0, stream>>>(Xt, Ob, g1 + vo, beta1 + vo, Xt);
    // FFN1: [4096,512] x [512,2048] -> gelu bf16, 16x32 = 512 blocks (128x128 tiles)
    mfma_gemm<128,128,1><<<dim3(DFF/128, M/128), 256, 0, stream>>>(
        Xt, W1t + (size_t)l*DFF*DM, bf1 + (size_t)l*DFF, nullptr, nullptr, H, M, DFF, DM);
    // FFN2: [4096,2048] x [2048,512] -> bf16 delta Yb (residual added in ln2)
    mfma_gemm<64,64,3><<<dim3(DM/64, M/64), 256, 0, stream>>>(
        H, W2t + (size_t)l*DM*DFF, bf2 + vo, nullptr, nullptr, Yb, M, DM, DFF);
    ln_kernel<<<M/8, 512, 0, stream>>>(Xt, Yb, g2 + vo, beta2 + vo, Xt);
  }
  ln_kernel<<<M/8, 512, 0, stream>>>(Xt, nullptr, gf, betaf, Xt);
  poolp_kernel<<<B_*64, 512, 0, stream>>>(Xt, pooledP);
  cls_kernel<<<40, 64, 0, stream>>>(pooledP, Wc, bc, out);
}